// Round 10
// baseline (496.432 us; speedup 1.0000x reference)
//
#include <hip/hip_runtime.h>
#include <math.h>

#define H 128
#define DXI 8
#define NNODES 100000
#define NEDGES 1000000
#define NRUNS (NEDGES / 64)
#define NDOM 32768
#define NBND 8192
#define NPTS (NDOM + NBND)
#define INV_RE 1.45e-05f
#define NODE_BLOCKS 1024

#define NSB ((NNODES + 1023) / 1024)   // scan blocks (1024 elems each) = 98

// d_out layout (floats): out_sup[300000] | continuity[32768] | momx[32768] | momy[32768] | boundary[8192]
#define CONT_OFF (NNODES * 3)
#define MOMX_OFF (CONT_OFF + NDOM)
#define MOMY_OFF (MOMX_OFF + NDOM)
#define BND_OFF  (MOMY_OFF + NDOM)

// fast tanh: 1 - 2/(exp2(2x*log2e)+1). Saturates correctly at +/-inf.
__device__ __forceinline__ float fast_tanh(float x) {
    const float e = __builtin_amdgcn_exp2f(x * 2.88539008f);
    return fmaf(-2.f, __builtin_amdgcn_rcpf(e + 1.f), 1.f);
}

// pack two floats to bf16 pair (RNE), low word = a, high word = b
__device__ __forceinline__ unsigned pack_bf16(float a, float b) {
    unsigned ua = __float_as_uint(a), ub = __float_as_uint(b);
    ua += 0x7fffu + ((ua >> 16) & 1u);
    ub += 0x7fffu + ((ub >> 16) & 1u);
    return (ua >> 16) | (ub & 0xffff0000u);
}

// ---------------------------------------------------------------------------
// hist + pack (fused): histogram of dst nodes; node record xb.
// ---------------------------------------------------------------------------
__global__ __launch_bounds__(256) void hist_pack_kernel(
    const int* __restrict__ eidx, const float* __restrict__ x,
    const float* __restrict__ pos, int* __restrict__ counts,
    uint4* __restrict__ xb)
{
    const int gid = blockIdx.x * 256 + threadIdx.x;
    for (int n = gid; n < NNODES; n += gridDim.x * 256) {
        const float4* xr = (const float4*)(x + (size_t)n * DXI);
        const float4 a = xr[0], b = xr[1];
        uint4 u;
        u.x = pack_bf16(a.x, a.y);
        u.y = pack_bf16(a.z, a.w);
        u.z = pack_bf16(b.x, b.y);
        u.w = pack_bf16(b.z, b.w);
        xb[(size_t)n * 2] = u;
        float4 c;
        c.x = pos[(size_t)n * 3];
        c.y = pos[(size_t)n * 3 + 1];
        c.z = 0.f; c.w = 0.f;
        xb[(size_t)n * 2 + 1] = *(const uint4*)&c;
    }
    const int* dst = eidx + NEDGES;
    for (int e = gid; e < NEDGES; e += gridDim.x * 256)
        atomicAdd(&counts[dst[e]], 1);
}

// ---------------------------------------------------------------------------
// CSR build pass 2a: per-block exclusive scan (1024 elems/block).
// ---------------------------------------------------------------------------
__global__ __launch_bounds__(256) void scan1_kernel(
    const int* __restrict__ counts, int* __restrict__ excl, int* __restrict__ bsum)
{
    const int tid = threadIdx.x, b = blockIdx.x;
    const int base = b * 1024 + tid * 4;
    int v0 = 0, v1 = 0, v2 = 0, v3 = 0;
    if (base + 3 < NNODES) {
        const int4 t = *(const int4*)(counts + base);
        v0 = t.x; v1 = t.y; v2 = t.z; v3 = t.w;
    } else {
        if (base     < NNODES) v0 = counts[base];
        if (base + 1 < NNODES) v1 = counts[base + 1];
        if (base + 2 < NNODES) v2 = counts[base + 2];
        if (base + 3 < NNODES) v3 = counts[base + 3];
    }
    const int own = v0 + v1 + v2 + v3;
    int s = own;
    const int lane = tid & 63, wv = tid >> 6;
#pragma unroll
    for (int d = 1; d < 64; d <<= 1) {
        const int t = __shfl_up(s, d);
        if (lane >= d) s += t;
    }
    __shared__ int wsum[4];
    if (lane == 63) wsum[wv] = s;
    __syncthreads();
    int woff = 0;
    for (int w = 0; w < wv; ++w) woff += wsum[w];
    const int e0 = s - own + woff;
    const int e1 = e0 + v0, e2 = e1 + v1, e3 = e2 + v2;
    if (base + 3 < NNODES) {
        *(int4*)(excl + base) = make_int4(e0, e1, e2, e3);
    } else {
        if (base     < NNODES) excl[base]     = e0;
        if (base + 1 < NNODES) excl[base + 1] = e1;
        if (base + 2 < NNODES) excl[base + 2] = e2;
        if (base + 3 < NNODES) excl[base + 3] = e3;
    }
    if (tid == 0) bsum[b] = wsum[0] + wsum[1] + wsum[2] + wsum[3];
}

// ---------------------------------------------------------------------------
// CSR build pass 2b: exclusive scan of block totals (1 block).
// ---------------------------------------------------------------------------
__global__ __launch_bounds__(128) void scan2_kernel(int* __restrict__ bsum)
{
    const int tid = threadIdx.x;
    int v = (tid < NSB) ? bsum[tid] : 0;
    const int own = v;
    const int lane = tid & 63, wv = tid >> 6;
#pragma unroll
    for (int d = 1; d < 64; d <<= 1) {
        const int t = __shfl_up(v, d);
        if (lane >= d) v += t;
    }
    __shared__ int ws2[2];
    if (lane == 63) ws2[wv] = v;
    __syncthreads();
    if (wv == 1) v += ws2[0];
    if (tid < NSB) bsum[tid] = v - own;
}

// ---------------------------------------------------------------------------
// CSR build pass 2c: add block offsets; produce cursor[].
// ---------------------------------------------------------------------------
__global__ __launch_bounds__(256) void scan3_kernel(
    int* __restrict__ offsets, int* __restrict__ cursor, const int* __restrict__ bsum)
{
    const int tid = threadIdx.x, b = blockIdx.x;
    const int base = b * 1024 + tid * 4;
    const int add = bsum[b];
    if (base + 3 < NNODES) {
        int4 t = *(const int4*)(offsets + base);
        t.x += add; t.y += add; t.z += add; t.w += add;
        *(int4*)(offsets + base) = t;
        *(int4*)(cursor + base) = t;
    } else {
        for (int i = 0; i < 4; ++i)
            if (base + i < NNODES) {
                const int t = offsets[base + i] + add;
                offsets[base + i] = t;
                cursor[base + i] = t;
            }
    }
}

// ---------------------------------------------------------------------------
// CSR build pass 3: scatter self-contained edge records into dst-sorted
// order:  uint4{ src, dst, bf16(e0,e1), bf16(e3, 0) }  (one 16B store).
// ---------------------------------------------------------------------------
__global__ __launch_bounds__(256) void scatter_kernel(
    const int* __restrict__ eidx, const float* __restrict__ eattr,
    int* __restrict__ cursor, uint4* __restrict__ csrE)
{
    const int* dst = eidx + NEDGES;
    for (int e = blockIdx.x * 256 + threadIdx.x; e < NEDGES; e += gridDim.x * 256) {
        const int d = dst[e];
        const float4 ea = ((const float4*)eattr)[e];
        const int slot = atomicAdd(&cursor[d], 1);
        uint4 r;
        r.x = (unsigned)eidx[e];
        r.y = (unsigned)d;
        r.z = pack_bf16(ea.x, ea.y);
        r.w = pack_bf16(ea.w, 0.f);
        csrE[slot] = r;
    }
}

// ---------------------------------------------------------------------------
// Segmented edge kernel: one WAVE per 64-edge dst-sorted run.
// ---------------------------------------------------------------------------
__global__ __launch_bounds__(256) void seg_edge_kernel(
    const uint4* __restrict__ csrE, const uint4* __restrict__ xb,
    const float* __restrict__ We, const float* __restrict__ Wx,
    const float* __restrict__ Wp, unsigned* __restrict__ agg)
{
    const int run = blockIdx.x * 4 + (threadIdx.x >> 6);
    if (run >= NRUNS) return;
    const int lane = threadIdx.x & 63;
    const int c0 = lane * 2, c1 = c0 + 1;

    float wxa[DXI], wxb_[DXI];
#pragma unroll
    for (int k = 0; k < DXI; ++k) { wxa[k] = Wx[k * H + c0]; wxb_[k] = Wx[k * H + c1]; }
    const float wp00 = Wp[c0], wp01 = Wp[H + c0];
    const float wp10 = Wp[c1], wp11 = Wp[H + c1];
    const float wea0 = We[c0], wea1 = We[H + c0], wea2 = We[2 * H + c0];
    const float web0 = We[c1], web1 = We[H + c1], web2 = We[2 * H + c1];

    const uint4 rec = csrE[(size_t)run * 64 + lane];
    const int s = (int)rec.x;
    const int mydst = (int)rec.y;
    const uint4 xa = xb[(size_t)s * 2];
    const float4 xc = *(const float4*)(xb + (size_t)s * 2 + 1);

    float acc0 = 0.f, acc1 = 0.f;
    bool first = true;
    int cur = __builtin_amdgcn_readlane(mydst, 0);

    for (int e = 0; e < 64; ++e) {
        const unsigned ue01 = (unsigned)__builtin_amdgcn_readlane((int)rec.z, e);
        const unsigned ue3  = (unsigned)__builtin_amdgcn_readlane((int)rec.w, e);
        const unsigned u01 = (unsigned)__builtin_amdgcn_readlane((int)xa.x, e);
        const unsigned u23 = (unsigned)__builtin_amdgcn_readlane((int)xa.y, e);
        const unsigned u45 = (unsigned)__builtin_amdgcn_readlane((int)xa.z, e);
        const unsigned u67 = (unsigned)__builtin_amdgcn_readlane((int)xa.w, e);
        const float spx = __int_as_float(__builtin_amdgcn_readlane(__float_as_int(xc.x), e));
        const float spy = __int_as_float(__builtin_amdgcn_readlane(__float_as_int(xc.y), e));

        const float e0f = __uint_as_float(ue01 << 16);
        const float e1f = __uint_as_float(ue01 & 0xffff0000u);
        const float e3f = __uint_as_float(ue3 << 16);
        const float x0 = __uint_as_float(u01 << 16);
        const float x1 = __uint_as_float(u01 & 0xffff0000u);
        const float x2 = __uint_as_float(u23 << 16);
        const float x3 = __uint_as_float(u23 & 0xffff0000u);
        const float x4 = __uint_as_float(u45 << 16);
        const float x5 = __uint_as_float(u45 & 0xffff0000u);
        const float x6 = __uint_as_float(u67 << 16);
        const float x7 = __uint_as_float(u67 & 0xffff0000u);

        float a0 = fmaf(wp00, spx, wp01 * spy);
        float a1 = fmaf(wp10, spx, wp11 * spy);
        a0 = fmaf(x0, wxa[0], a0); a1 = fmaf(x0, wxb_[0], a1);
        a0 = fmaf(x1, wxa[1], a0); a1 = fmaf(x1, wxb_[1], a1);
        a0 = fmaf(x2, wxa[2], a0); a1 = fmaf(x2, wxb_[2], a1);
        a0 = fmaf(x3, wxa[3], a0); a1 = fmaf(x3, wxb_[3], a1);
        a0 = fmaf(x4, wxa[4], a0); a1 = fmaf(x4, wxb_[4], a1);
        a0 = fmaf(x5, wxa[5], a0); a1 = fmaf(x5, wxb_[5], a1);
        a0 = fmaf(x6, wxa[6], a0); a1 = fmaf(x6, wxb_[6], a1);
        a0 = fmaf(x7, wxa[7], a0); a1 = fmaf(x7, wxb_[7], a1);
        const float w0 = fmaf(e0f, wea0, fmaf(e1f, wea1, e3f * wea2));
        const float w1 = fmaf(e0f, web0, fmaf(e1f, web1, e3f * web2));
        acc0 = fmaf(fast_tanh(a0), w0, acc0);
        acc1 = fmaf(fast_tanh(a1), w1, acc1);

        const int nxt = (e < 63) ? __builtin_amdgcn_readlane(mydst, e + 1) : -1;
        if (nxt != cur) {
            unsigned* p = agg + (size_t)cur * 64 + lane;
            if (first || e == 63) {
                unsigned old = *p;
                while (true) {
                    const float g0 = __uint_as_float(old << 16) + acc0;
                    const float g1 = __uint_as_float(old & 0xffff0000u) + acc1;
                    const unsigned nw = pack_bf16(g0, g1);
                    const unsigned prev = atomicCAS(p, old, nw);
                    if (prev == old) break;
                    old = prev;
                }
            } else {
                *p = pack_bf16(acc0, acc1);
            }
            acc0 = 0.f; acc1 = 0.f;
            first = false;
            cur = nxt;
        }
    }
}

// ---------------------------------------------------------------------------
// Node kernel: wave per node, 2ch/lane. ctx via LDS reduce + per-block row.
// ---------------------------------------------------------------------------
__global__ __launch_bounds__(256) void node_kernel(
    const float* __restrict__ x, const float* __restrict__ pos,
    const unsigned* __restrict__ agg,
    const float* __restrict__ Wx, const float* __restrict__ Wp,
    const float* __restrict__ Wout,
    float* __restrict__ out_sup, float* __restrict__ ctx_part)
{
    const int lane = threadIdx.x & 63;
    const int wv   = threadIdx.x >> 6;
    const int c0 = lane * 2, c1 = c0 + 1;

    float wxa[DXI], wxb_[DXI];
#pragma unroll
    for (int k = 0; k < DXI; ++k) { wxa[k] = Wx[k * H + c0]; wxb_[k] = Wx[k * H + c1]; }
    const float wp00 = Wp[c0], wp01 = Wp[H + c0];
    const float wp10 = Wp[c1], wp11 = Wp[H + c1];
    const float woa0 = Wout[c0 * 3], woa1 = Wout[c0 * 3 + 1], woa2 = Wout[c0 * 3 + 2];
    const float wob0 = Wout[c1 * 3], wob1 = Wout[c1 * 3 + 1], wob2 = Wout[c1 * 3 + 2];

    float ctx0 = 0.f, ctx1 = 0.f;

    for (int n = blockIdx.x * 4 + wv; n < NNODES; n += gridDim.x * 4) {
        const unsigned ag = agg[(size_t)n * 64 + lane];
        const float* xr = x + (size_t)n * DXI;
        const float px = pos[(size_t)n * 3], py = pos[(size_t)n * 3 + 1];
        float a0 = fmaf(wp00, px, wp01 * py);
        float a1 = fmaf(wp10, px, wp11 * py);
#pragma unroll
        for (int k = 0; k < DXI; ++k) {
            const float xv = xr[k];
            a0 = fmaf(xv, wxa[k], a0);
            a1 = fmaf(xv, wxb_[k], a1);
        }
        const float h0 = fast_tanh(fast_tanh(a0) + __uint_as_float(ag << 16));
        const float h1 = fast_tanh(fast_tanh(a1) + __uint_as_float(ag & 0xffff0000u));
        ctx0 += h0; ctx1 += h1;

        float p0 = fmaf(h0, woa0, h1 * wob0);
        float p1 = fmaf(h0, woa1, h1 * wob1);
        float p2 = fmaf(h0, woa2, h1 * wob2);
#pragma unroll
        for (int m = 32; m; m >>= 1) {
            p0 += __shfl_xor(p0, m);
            p1 += __shfl_xor(p1, m);
            p2 += __shfl_xor(p2, m);
        }
        if (lane == 0) {
            out_sup[(size_t)n * 3 + 0] = p0;
            out_sup[(size_t)n * 3 + 1] = p1;
            out_sup[(size_t)n * 3 + 2] = p2;
        }
    }

    __shared__ float part[4][H];
    part[wv][c0] = ctx0;
    part[wv][c1] = ctx1;
    __syncthreads();
    if (threadIdx.x < H) {
        const int ch = threadIdx.x;
        ctx_part[(size_t)blockIdx.x * H + ch] =
            part[0][ch] + part[1][ch] + part[2][ch] + part[3][ch];
    }
}

// ---------------------------------------------------------------------------
// ctx finalize: sum per-block partial rows, then tab rows.
// ---------------------------------------------------------------------------
__global__ __launch_bounds__(128) void ctx_kernel(
    const float* __restrict__ ctx_part, const float* __restrict__ W1,
    const float* __restrict__ b1, float* __restrict__ tab)
{
    __shared__ float ctx[H];
    const int ch = threadIdx.x;
    float s0 = 0.f, s1 = 0.f, s2 = 0.f, s3 = 0.f;
#pragma unroll 4
    for (int b = 0; b < NODE_BLOCKS; b += 4) {
        s0 += ctx_part[(size_t)(b + 0) * H + ch];
        s1 += ctx_part[(size_t)(b + 1) * H + ch];
        s2 += ctx_part[(size_t)(b + 2) * H + ch];
        s3 += ctx_part[(size_t)(b + 3) * H + ch];
    }
    ctx[ch] = (s0 + s1 + s2 + s3) * (1.0f / (float)NNODES);
    __syncthreads();
    float acc = b1[ch];
    for (int k = 0; k < H; ++k) acc = fmaf(ctx[k], W1[(size_t)(2 + k) * H + ch], acc);
    const float A0 = W1[ch], A1 = W1[H + ch];
    tab[ch * 8 + 0] = A0;
    tab[ch * 8 + 1] = A1;
    tab[ch * 8 + 2] = acc;
    tab[ch * 8 + 3] = A0 * A0;
    tab[ch * 8 + 4] = A1 * A1;
    tab[ch * 8 + 5] = 0.f;
    tab[ch * 8 + 6] = 0.f;
    tab[ch * 8 + 7] = 0.f;
}

// ---------------------------------------------------------------------------
// Sampling kernel v3: software-prefetched W2 row (breaks load->FMA dep),
// unroll 2, occupancy cap 4 waves/EU. Thread = (point, 16-j group).
// ---------------------------------------------------------------------------
__global__ __launch_bounds__(256, 4) void samp_kernel(
    const float* __restrict__ dom, const float* __restrict__ bnd,
    const int* __restrict__ bidx,
    const float* __restrict__ x, const float* __restrict__ xmask,
    const float* __restrict__ tab,
    const float* __restrict__ W2, const float* __restrict__ b2,
    const float* __restrict__ W3, float* __restrict__ out)
{
    const int tid = threadIdx.x;
    const int jg  = tid & 7;
    const int pl  = tid >> 3;
    const int p   = blockIdx.x * 32 + pl;
    const int j0  = jg * 16;

    float spx, spy;
    if (p < NDOM) { spx = dom[(size_t)p * 2];          spy = dom[(size_t)p * 2 + 1]; }
    else          { spx = bnd[(size_t)(p - NDOM) * 2]; spy = bnd[(size_t)(p - NDOM) * 2 + 1]; }

    float a2[16], d2x[16], d2y[16], exx[16], eyy[16];
#pragma unroll
    for (int jj = 0; jj < 16; ++jj) {
        a2[jj] = b2[j0 + jj];
        d2x[jj] = 0.f; d2y[jj] = 0.f; exx[jj] = 0.f; eyy[jj] = 0.f;
    }

    // prime the W2-row pipeline
    float4 w4[4];
    {
        const float4* wr = (const float4*)(W2 + j0);
        w4[0] = wr[0]; w4[1] = wr[1]; w4[2] = wr[2]; w4[3] = wr[3];
    }

#pragma unroll 2
    for (int k = 0; k < H; ++k) {
        // prefetch next row (clamped; row 127 reloads itself, unused)
        const int kn = (k + 1 < H) ? k + 1 : k;
        const float4* wrn = (const float4*)(W2 + (size_t)kn * H + j0);
        float4 w4n0 = wrn[0], w4n1 = wrn[1], w4n2 = wrn[2], w4n3 = wrn[3];

        const float4 t4 = *(const float4*)(tab + (size_t)k * 8);
        const float A1s = tab[(size_t)k * 8 + 4];
        const float A0 = t4.x, A1 = t4.y, cc = t4.z, A0s = t4.w;

        const float a1 = fmaf(spx, A0, fmaf(spy, A1, cc));
        const float e  = __builtin_amdgcn_exp2f(a1 * 2.88539008f);
        const float h1 = fmaf(-2.f, __builtin_amdgcn_rcpf(e + 1.f), 1.f);
        const float t1 = fmaf(-h1, h1, 1.f);
        const float m2 = -2.f * h1 * t1;
        const float g1x = t1 * A0, g1y = t1 * A1;
        const float sxx = m2 * A0s, syy = m2 * A1s;

        const float* wf = (const float*)w4;
#pragma unroll
        for (int jj = 0; jj < 16; ++jj) {
            const float w = wf[jj];
            a2[jj]  = fmaf(h1,  w, a2[jj]);
            d2x[jj] = fmaf(g1x, w, d2x[jj]);
            d2y[jj] = fmaf(g1y, w, d2y[jj]);
            exx[jj] = fmaf(sxx, w, exx[jj]);
            eyy[jj] = fmaf(syy, w, eyy[jj]);
        }
        w4[0] = w4n0; w4[1] = w4n1; w4[2] = w4n2; w4[3] = w4n3;
    }

    float r[13];
#pragma unroll
    for (int i = 0; i < 13; ++i) r[i] = 0.f;
#pragma unroll
    for (int jj = 0; jj < 16; ++jj) {
        const float h2 = fast_tanh(a2[jj]);
        const float t2 = fmaf(-h2, h2, 1.f);
        const float gx = t2 * d2x[jj];
        const float gy = t2 * d2y[jj];
        const float hxx = fmaf(-2.f * h2 * gx, d2x[jj], t2 * exx[jj]);
        const float hyy = fmaf(-2.f * h2 * gy, d2y[jj], t2 * eyy[jj]);
        const int j = j0 + jj;
        const float w30 = W3[j * 3], w31 = W3[j * 3 + 1], w32 = W3[j * 3 + 2];
        r[0]  = fmaf(h2, w30, r[0]);   r[1]  = fmaf(h2, w31, r[1]);   r[2] = fmaf(h2, w32, r[2]);
        r[3]  = fmaf(gx, w30, r[3]);   r[4]  = fmaf(gx, w31, r[4]);   r[5] = fmaf(gx, w32, r[5]);
        r[6]  = fmaf(gy, w30, r[6]);   r[7]  = fmaf(gy, w31, r[7]);   r[8] = fmaf(gy, w32, r[8]);
        r[9]  = fmaf(hxx, w30, r[9]);  r[10] = fmaf(hxx, w31, r[10]);
        r[11] = fmaf(hyy, w30, r[11]); r[12] = fmaf(hyy, w31, r[12]);
    }

#pragma unroll
    for (int m = 1; m < 8; m <<= 1)
#pragma unroll
        for (int i = 0; i < 13; ++i) r[i] += __shfl_xor(r[i], m);

    if (jg == 0) {
        const float u = r[0], v = r[1], pp = r[2];
        const float ux = r[3], vx = r[4], px = r[5];
        const float uy = r[6], vy = r[7], py = r[8];
        const float uxx = r[9], vxx = r[10], uyy = r[11], vyy = r[12];
        if (p < NDOM) {
            out[CONT_OFF + p] = ux + vy;
            out[MOMX_OFF + p] = fmaf(u, ux, fmaf(v, uy, px)) - (uxx + uyy) * INV_RE;
            out[MOMY_OFF + p] = fmaf(u, vx, fmaf(v, vy, py)) - (vxx + vyy) * INV_RE;
        } else {
            const int i = p - NDOM;
            const int idx = bidx[i];
            const float* xbp = x + (size_t)idx * DXI;
            const float* mm = xmask + (size_t)idx * 6;
            const float tx = xbp[0], ty = xbp[1];
            const float nx = -ty, ny = tx;
            const float r_vt = fabsf(tx * u + ty * v - xbp[2]) * mm[1];
            const float r_vn = fabsf(nx * u + ny * v - xbp[3]) * mm[2];
            const float r_p  = fabsf(pp - xbp[4]) * mm[3];
            const float r_dv = fabsf(nx * ux + ny * vy - xbp[5]) * mm[4];
            const float r_dp = fabsf(nx * px + ny * py - xbp[6]) * mm[5];
            const float c = mm[1] + mm[2] + mm[3] + mm[4] + mm[5];
            out[BND_OFF + i] = (r_vt + r_vn + r_p + r_dv + r_dp) / c;
        }
    }
}

extern "C" void kernel_launch(void* const* d_in, const int* in_sizes, int n_in,
                              void* d_out, int out_size, void* d_ws, size_t ws_size,
                              hipStream_t stream) {
    const float* x     = (const float*)d_in[0];
    const float* xmask = (const float*)d_in[1];
    const int*   eidx  = (const int*)d_in[2];
    const float* eattr = (const float*)d_in[3];
    const float* pos   = (const float*)d_in[4];
    const float* dom   = (const float*)d_in[6];
    const float* bnd   = (const float*)d_in[7];
    const int*   bidx  = (const int*)d_in[8];
    const float* Wx    = (const float*)d_in[9];
    const float* Wp    = (const float*)d_in[10];
    const float* We    = (const float*)d_in[11];
    const float* Wout  = (const float*)d_in[12];
    const float* W1    = (const float*)d_in[13];
    const float* b1    = (const float*)d_in[14];
    const float* W2    = (const float*)d_in[15];
    const float* b2    = (const float*)d_in[16];
    const float* W3    = (const float*)d_in[17];

    float* out = (float*)d_out;

    // workspace layout (16B-aligned sections): total ~46.5 MB
    int*      counts   = (int*)d_ws;                    // NNODES
    int*      offsets  = counts + NNODES;               // NNODES + 8
    int*      cursor   = offsets + NNODES + 8;          // NNODES
    int*      bsum     = cursor + NNODES;               // 128
    uint4*    csrE     = (uint4*)(bsum + 128);          // NEDGES (16 MB)
    uint4*    xb       = (uint4*)(csrE + NEDGES);       // NNODES*2 (3.2 MB)
    unsigned* agg      = (unsigned*)(xb + (size_t)NNODES * 2); // NNODES*64 (25.6 MB)
    float*    ctx_part = (float*)(agg + (size_t)NNODES * 64);  // NODE_BLOCKS*H (512 KB)
    float*    tab      = ctx_part + (size_t)NODE_BLOCKS * H;   // H*8

    (void)hipMemsetAsync(counts, 0, (size_t)NNODES * sizeof(int), stream);
    (void)hipMemsetAsync(agg, 0, (size_t)NNODES * 64 * sizeof(unsigned), stream);

    hist_pack_kernel<<<512, 256, 0, stream>>>(eidx, x, pos, counts, xb);
    scan1_kernel<<<NSB, 256, 0, stream>>>(counts, offsets, bsum);
    scan2_kernel<<<1, 128, 0, stream>>>(bsum);
    scan3_kernel<<<NSB, 256, 0, stream>>>(offsets, cursor, bsum);
    scatter_kernel<<<512, 256, 0, stream>>>(eidx, eattr, cursor, csrE);
    seg_edge_kernel<<<(NRUNS + 3) / 4, 256, 0, stream>>>(csrE, xb, We, Wx, Wp, agg);
    node_kernel<<<NODE_BLOCKS, 256, 0, stream>>>(x, pos, agg, Wx, Wp, Wout, out, ctx_part);
    ctx_kernel<<<1, H, 0, stream>>>(ctx_part, W1, b1, tab);
    samp_kernel<<<1280, 256, 0, stream>>>(dom, bnd, bidx, x, xmask, tab, W2, b2, W3, out);
}

// Round 11
// 370.037 us; speedup vs baseline: 1.3416x; 1.3416x over previous
//
#include <hip/hip_runtime.h>
#include <math.h>

#define H 128
#define DXI 8
#define NNODES 100000
#define NEDGES 1000000
#define NRUNS (NEDGES / 64)
#define NDOM 32768
#define NBND 8192
#define NPTS (NDOM + NBND)
#define INV_RE 1.45e-05f
#define NODE_BLOCKS 1024

#define NSB ((NNODES + 1023) / 1024)   // scan blocks (1024 elems each) = 98

// d_out layout (floats): out_sup[300000] | continuity[32768] | momx[32768] | momy[32768] | boundary[8192]
#define CONT_OFF (NNODES * 3)
#define MOMX_OFF (CONT_OFF + NDOM)
#define MOMY_OFF (MOMX_OFF + NDOM)
#define BND_OFF  (MOMY_OFF + NDOM)

// fast tanh: 1 - 2/(exp2(2x*log2e)+1). Saturates correctly at +/-inf.
__device__ __forceinline__ float fast_tanh(float x) {
    const float e = __builtin_amdgcn_exp2f(x * 2.88539008f);
    return fmaf(-2.f, __builtin_amdgcn_rcpf(e + 1.f), 1.f);
}

// pack two floats to bf16 pair (RNE), low word = a, high word = b
__device__ __forceinline__ unsigned pack_bf16(float a, float b) {
    unsigned ua = __float_as_uint(a), ub = __float_as_uint(b);
    ua += 0x7fffu + ((ua >> 16) & 1u);
    ub += 0x7fffu + ((ub >> 16) & 1u);
    return (ua >> 16) | (ub & 0xffff0000u);
}

// ---------------------------------------------------------------------------
// hist + pack (fused): histogram of dst nodes; node record xb.
// ---------------------------------------------------------------------------
__global__ __launch_bounds__(256) void hist_pack_kernel(
    const int* __restrict__ eidx, const float* __restrict__ x,
    const float* __restrict__ pos, int* __restrict__ counts,
    uint4* __restrict__ xb)
{
    const int gid = blockIdx.x * 256 + threadIdx.x;
    for (int n = gid; n < NNODES; n += gridDim.x * 256) {
        const float4* xr = (const float4*)(x + (size_t)n * DXI);
        const float4 a = xr[0], b = xr[1];
        uint4 u;
        u.x = pack_bf16(a.x, a.y);
        u.y = pack_bf16(a.z, a.w);
        u.z = pack_bf16(b.x, b.y);
        u.w = pack_bf16(b.z, b.w);
        xb[(size_t)n * 2] = u;
        float4 c;
        c.x = pos[(size_t)n * 3];
        c.y = pos[(size_t)n * 3 + 1];
        c.z = 0.f; c.w = 0.f;
        xb[(size_t)n * 2 + 1] = *(const uint4*)&c;
    }
    const int* dst = eidx + NEDGES;
    for (int e = gid; e < NEDGES; e += gridDim.x * 256)
        atomicAdd(&counts[dst[e]], 1);
}

// ---------------------------------------------------------------------------
// CSR build pass 2a: per-block exclusive scan (1024 elems/block).
// ---------------------------------------------------------------------------
__global__ __launch_bounds__(256) void scan1_kernel(
    const int* __restrict__ counts, int* __restrict__ excl, int* __restrict__ bsum)
{
    const int tid = threadIdx.x, b = blockIdx.x;
    const int base = b * 1024 + tid * 4;
    int v0 = 0, v1 = 0, v2 = 0, v3 = 0;
    if (base + 3 < NNODES) {
        const int4 t = *(const int4*)(counts + base);
        v0 = t.x; v1 = t.y; v2 = t.z; v3 = t.w;
    } else {
        if (base     < NNODES) v0 = counts[base];
        if (base + 1 < NNODES) v1 = counts[base + 1];
        if (base + 2 < NNODES) v2 = counts[base + 2];
        if (base + 3 < NNODES) v3 = counts[base + 3];
    }
    const int own = v0 + v1 + v2 + v3;
    int s = own;
    const int lane = tid & 63, wv = tid >> 6;
#pragma unroll
    for (int d = 1; d < 64; d <<= 1) {
        const int t = __shfl_up(s, d);
        if (lane >= d) s += t;
    }
    __shared__ int wsum[4];
    if (lane == 63) wsum[wv] = s;
    __syncthreads();
    int woff = 0;
    for (int w = 0; w < wv; ++w) woff += wsum[w];
    const int e0 = s - own + woff;
    const int e1 = e0 + v0, e2 = e1 + v1, e3 = e2 + v2;
    if (base + 3 < NNODES) {
        *(int4*)(excl + base) = make_int4(e0, e1, e2, e3);
    } else {
        if (base     < NNODES) excl[base]     = e0;
        if (base + 1 < NNODES) excl[base + 1] = e1;
        if (base + 2 < NNODES) excl[base + 2] = e2;
        if (base + 3 < NNODES) excl[base + 3] = e3;
    }
    if (tid == 0) bsum[b] = wsum[0] + wsum[1] + wsum[2] + wsum[3];
}

// ---------------------------------------------------------------------------
// CSR build pass 2b: exclusive scan of block totals (1 block).
// ---------------------------------------------------------------------------
__global__ __launch_bounds__(128) void scan2_kernel(int* __restrict__ bsum)
{
    const int tid = threadIdx.x;
    int v = (tid < NSB) ? bsum[tid] : 0;
    const int own = v;
    const int lane = tid & 63, wv = tid >> 6;
#pragma unroll
    for (int d = 1; d < 64; d <<= 1) {
        const int t = __shfl_up(v, d);
        if (lane >= d) v += t;
    }
    __shared__ int ws2[2];
    if (lane == 63) ws2[wv] = v;
    __syncthreads();
    if (wv == 1) v += ws2[0];
    if (tid < NSB) bsum[tid] = v - own;
}

// ---------------------------------------------------------------------------
// CSR build pass 2c: add block offsets; produce cursor[].
// ---------------------------------------------------------------------------
__global__ __launch_bounds__(256) void scan3_kernel(
    int* __restrict__ offsets, int* __restrict__ cursor, const int* __restrict__ bsum)
{
    const int tid = threadIdx.x, b = blockIdx.x;
    const int base = b * 1024 + tid * 4;
    const int add = bsum[b];
    if (base + 3 < NNODES) {
        int4 t = *(const int4*)(offsets + base);
        t.x += add; t.y += add; t.z += add; t.w += add;
        *(int4*)(offsets + base) = t;
        *(int4*)(cursor + base) = t;
    } else {
        for (int i = 0; i < 4; ++i)
            if (base + i < NNODES) {
                const int t = offsets[base + i] + add;
                offsets[base + i] = t;
                cursor[base + i] = t;
            }
    }
}

// ---------------------------------------------------------------------------
// CSR build pass 3: scatter self-contained edge records into dst-sorted
// order:  uint4{ src, dst, bf16(e0,e1), bf16(e3, 0) }  (one 16B store).
// ---------------------------------------------------------------------------
__global__ __launch_bounds__(256) void scatter_kernel(
    const int* __restrict__ eidx, const float* __restrict__ eattr,
    int* __restrict__ cursor, uint4* __restrict__ csrE)
{
    const int* dst = eidx + NEDGES;
    for (int e = blockIdx.x * 256 + threadIdx.x; e < NEDGES; e += gridDim.x * 256) {
        const int d = dst[e];
        const float4 ea = ((const float4*)eattr)[e];
        const int slot = atomicAdd(&cursor[d], 1);
        uint4 r;
        r.x = (unsigned)eidx[e];
        r.y = (unsigned)d;
        r.z = pack_bf16(ea.x, ea.y);
        r.w = pack_bf16(ea.w, 0.f);
        csrE[slot] = r;
    }
}

// ---------------------------------------------------------------------------
// Segmented edge kernel: one WAVE per 64-edge dst-sorted run.
// ---------------------------------------------------------------------------
__global__ __launch_bounds__(256) void seg_edge_kernel(
    const uint4* __restrict__ csrE, const uint4* __restrict__ xb,
    const float* __restrict__ We, const float* __restrict__ Wx,
    const float* __restrict__ Wp, unsigned* __restrict__ agg)
{
    const int run = blockIdx.x * 4 + (threadIdx.x >> 6);
    if (run >= NRUNS) return;
    const int lane = threadIdx.x & 63;
    const int c0 = lane * 2, c1 = c0 + 1;

    float wxa[DXI], wxb_[DXI];
#pragma unroll
    for (int k = 0; k < DXI; ++k) { wxa[k] = Wx[k * H + c0]; wxb_[k] = Wx[k * H + c1]; }
    const float wp00 = Wp[c0], wp01 = Wp[H + c0];
    const float wp10 = Wp[c1], wp11 = Wp[H + c1];
    const float wea0 = We[c0], wea1 = We[H + c0], wea2 = We[2 * H + c0];
    const float web0 = We[c1], web1 = We[H + c1], web2 = We[2 * H + c1];

    const uint4 rec = csrE[(size_t)run * 64 + lane];
    const int s = (int)rec.x;
    const int mydst = (int)rec.y;
    const uint4 xa = xb[(size_t)s * 2];
    const float4 xc = *(const float4*)(xb + (size_t)s * 2 + 1);

    float acc0 = 0.f, acc1 = 0.f;
    bool first = true;
    int cur = __builtin_amdgcn_readlane(mydst, 0);

    for (int e = 0; e < 64; ++e) {
        const unsigned ue01 = (unsigned)__builtin_amdgcn_readlane((int)rec.z, e);
        const unsigned ue3  = (unsigned)__builtin_amdgcn_readlane((int)rec.w, e);
        const unsigned u01 = (unsigned)__builtin_amdgcn_readlane((int)xa.x, e);
        const unsigned u23 = (unsigned)__builtin_amdgcn_readlane((int)xa.y, e);
        const unsigned u45 = (unsigned)__builtin_amdgcn_readlane((int)xa.z, e);
        const unsigned u67 = (unsigned)__builtin_amdgcn_readlane((int)xa.w, e);
        const float spx = __int_as_float(__builtin_amdgcn_readlane(__float_as_int(xc.x), e));
        const float spy = __int_as_float(__builtin_amdgcn_readlane(__float_as_int(xc.y), e));

        const float e0f = __uint_as_float(ue01 << 16);
        const float e1f = __uint_as_float(ue01 & 0xffff0000u);
        const float e3f = __uint_as_float(ue3 << 16);
        const float x0 = __uint_as_float(u01 << 16);
        const float x1 = __uint_as_float(u01 & 0xffff0000u);
        const float x2 = __uint_as_float(u23 << 16);
        const float x3 = __uint_as_float(u23 & 0xffff0000u);
        const float x4 = __uint_as_float(u45 << 16);
        const float x5 = __uint_as_float(u45 & 0xffff0000u);
        const float x6 = __uint_as_float(u67 << 16);
        const float x7 = __uint_as_float(u67 & 0xffff0000u);

        float a0 = fmaf(wp00, spx, wp01 * spy);
        float a1 = fmaf(wp10, spx, wp11 * spy);
        a0 = fmaf(x0, wxa[0], a0); a1 = fmaf(x0, wxb_[0], a1);
        a0 = fmaf(x1, wxa[1], a0); a1 = fmaf(x1, wxb_[1], a1);
        a0 = fmaf(x2, wxa[2], a0); a1 = fmaf(x2, wxb_[2], a1);
        a0 = fmaf(x3, wxa[3], a0); a1 = fmaf(x3, wxb_[3], a1);
        a0 = fmaf(x4, wxa[4], a0); a1 = fmaf(x4, wxb_[4], a1);
        a0 = fmaf(x5, wxa[5], a0); a1 = fmaf(x5, wxb_[5], a1);
        a0 = fmaf(x6, wxa[6], a0); a1 = fmaf(x6, wxb_[6], a1);
        a0 = fmaf(x7, wxa[7], a0); a1 = fmaf(x7, wxb_[7], a1);
        const float w0 = fmaf(e0f, wea0, fmaf(e1f, wea1, e3f * wea2));
        const float w1 = fmaf(e0f, web0, fmaf(e1f, web1, e3f * web2));
        acc0 = fmaf(fast_tanh(a0), w0, acc0);
        acc1 = fmaf(fast_tanh(a1), w1, acc1);

        const int nxt = (e < 63) ? __builtin_amdgcn_readlane(mydst, e + 1) : -1;
        if (nxt != cur) {
            unsigned* p = agg + (size_t)cur * 64 + lane;
            if (first || e == 63) {
                unsigned old = *p;
                while (true) {
                    const float g0 = __uint_as_float(old << 16) + acc0;
                    const float g1 = __uint_as_float(old & 0xffff0000u) + acc1;
                    const unsigned nw = pack_bf16(g0, g1);
                    const unsigned prev = atomicCAS(p, old, nw);
                    if (prev == old) break;
                    old = prev;
                }
            } else {
                *p = pack_bf16(acc0, acc1);
            }
            acc0 = 0.f; acc1 = 0.f;
            first = false;
            cur = nxt;
        }
    }
}

// ---------------------------------------------------------------------------
// Node kernel: wave per node, 2ch/lane. ctx via LDS reduce + per-block row.
// ---------------------------------------------------------------------------
__global__ __launch_bounds__(256) void node_kernel(
    const float* __restrict__ x, const float* __restrict__ pos,
    const unsigned* __restrict__ agg,
    const float* __restrict__ Wx, const float* __restrict__ Wp,
    const float* __restrict__ Wout,
    float* __restrict__ out_sup, float* __restrict__ ctx_part)
{
    const int lane = threadIdx.x & 63;
    const int wv   = threadIdx.x >> 6;
    const int c0 = lane * 2, c1 = c0 + 1;

    float wxa[DXI], wxb_[DXI];
#pragma unroll
    for (int k = 0; k < DXI; ++k) { wxa[k] = Wx[k * H + c0]; wxb_[k] = Wx[k * H + c1]; }
    const float wp00 = Wp[c0], wp01 = Wp[H + c0];
    const float wp10 = Wp[c1], wp11 = Wp[H + c1];
    const float woa0 = Wout[c0 * 3], woa1 = Wout[c0 * 3 + 1], woa2 = Wout[c0 * 3 + 2];
    const float wob0 = Wout[c1 * 3], wob1 = Wout[c1 * 3 + 1], wob2 = Wout[c1 * 3 + 2];

    float ctx0 = 0.f, ctx1 = 0.f;

    for (int n = blockIdx.x * 4 + wv; n < NNODES; n += gridDim.x * 4) {
        const unsigned ag = agg[(size_t)n * 64 + lane];
        const float* xr = x + (size_t)n * DXI;
        const float px = pos[(size_t)n * 3], py = pos[(size_t)n * 3 + 1];
        float a0 = fmaf(wp00, px, wp01 * py);
        float a1 = fmaf(wp10, px, wp11 * py);
#pragma unroll
        for (int k = 0; k < DXI; ++k) {
            const float xv = xr[k];
            a0 = fmaf(xv, wxa[k], a0);
            a1 = fmaf(xv, wxb_[k], a1);
        }
        const float h0 = fast_tanh(fast_tanh(a0) + __uint_as_float(ag << 16));
        const float h1 = fast_tanh(fast_tanh(a1) + __uint_as_float(ag & 0xffff0000u));
        ctx0 += h0; ctx1 += h1;

        float p0 = fmaf(h0, woa0, h1 * wob0);
        float p1 = fmaf(h0, woa1, h1 * wob1);
        float p2 = fmaf(h0, woa2, h1 * wob2);
#pragma unroll
        for (int m = 32; m; m >>= 1) {
            p0 += __shfl_xor(p0, m);
            p1 += __shfl_xor(p1, m);
            p2 += __shfl_xor(p2, m);
        }
        if (lane == 0) {
            out_sup[(size_t)n * 3 + 0] = p0;
            out_sup[(size_t)n * 3 + 1] = p1;
            out_sup[(size_t)n * 3 + 2] = p2;
        }
    }

    __shared__ float part[4][H];
    part[wv][c0] = ctx0;
    part[wv][c1] = ctx1;
    __syncthreads();
    if (threadIdx.x < H) {
        const int ch = threadIdx.x;
        ctx_part[(size_t)blockIdx.x * H + ch] =
            part[0][ch] + part[1][ch] + part[2][ch] + part[3][ch];
    }
}

// ---------------------------------------------------------------------------
// ctx finalize: sum per-block partial rows, then tab rows.
// ---------------------------------------------------------------------------
__global__ __launch_bounds__(128) void ctx_kernel(
    const float* __restrict__ ctx_part, const float* __restrict__ W1,
    const float* __restrict__ b1, float* __restrict__ tab)
{
    __shared__ float ctx[H];
    const int ch = threadIdx.x;
    float s0 = 0.f, s1 = 0.f, s2 = 0.f, s3 = 0.f;
#pragma unroll 4
    for (int b = 0; b < NODE_BLOCKS; b += 4) {
        s0 += ctx_part[(size_t)(b + 0) * H + ch];
        s1 += ctx_part[(size_t)(b + 1) * H + ch];
        s2 += ctx_part[(size_t)(b + 2) * H + ch];
        s3 += ctx_part[(size_t)(b + 3) * H + ch];
    }
    ctx[ch] = (s0 + s1 + s2 + s3) * (1.0f / (float)NNODES);
    __syncthreads();
    float acc = b1[ch];
    for (int k = 0; k < H; ++k) acc = fmaf(ctx[k], W1[(size_t)(2 + k) * H + ch], acc);
    const float A0 = W1[ch], A1 = W1[H + ch];
    tab[ch * 8 + 0] = A0;
    tab[ch * 8 + 1] = A1;
    tab[ch * 8 + 2] = acc;
    tab[ch * 8 + 3] = A0 * A0;
    tab[ch * 8 + 4] = A1 * A1;
    tab[ch * 8 + 5] = 0.f;
    tab[ch * 8 + 6] = 0.f;
    tab[ch * 8 + 7] = 0.f;
}

// ---------------------------------------------------------------------------
// Sampling kernel v4: wave-per-j-chunk. Block = 512 thr = 8 waves; wave wv
// owns j in [wv*16, wv*16+16); lane = one point. All W2/tab/b2/W3 accesses
// are wave-uniform -> scalar-pipe loads; inner loop is pure register FMA.
// Cross-wave 13-value reduction via LDS (stride 13 -> conflict-free).
// ---------------------------------------------------------------------------
__global__ __launch_bounds__(512, 2) void samp_kernel(
    const float* __restrict__ dom, const float* __restrict__ bnd,
    const int* __restrict__ bidx,
    const float* __restrict__ x, const float* __restrict__ xmask,
    const float* __restrict__ tab,
    const float* __restrict__ W2, const float* __restrict__ b2,
    const float* __restrict__ W3, float* __restrict__ out)
{
    const int tid  = threadIdx.x;
    const int lane = tid & 63;
    const int wv   = __builtin_amdgcn_readfirstlane(tid >> 6);  // 0..7, uniform
    const int j0   = wv * 16;
    const int p    = blockIdx.x * 64 + lane;

    float spx, spy;
    if (p < NDOM) { spx = dom[(size_t)p * 2];          spy = dom[(size_t)p * 2 + 1]; }
    else          { spx = bnd[(size_t)(p - NDOM) * 2]; spy = bnd[(size_t)(p - NDOM) * 2 + 1]; }

    float a2[16], d2x[16], d2y[16], exx[16], eyy[16];
#pragma unroll
    for (int jj = 0; jj < 16; ++jj) {
        a2[jj] = b2[j0 + jj];          // uniform -> scalar load
        d2x[jj] = 0.f; d2y[jj] = 0.f; exx[jj] = 0.f; eyy[jj] = 0.f;
    }

    for (int k = 0; k < H; ++k) {
        const float* wrow = W2 + (size_t)k * H + j0;   // uniform
        float wbuf[16];
#pragma unroll
        for (int q = 0; q < 16; ++q) wbuf[q] = wrow[q];

        const float* trow = tab + (size_t)k * 8;       // uniform
        const float A0 = trow[0], A1 = trow[1], cc = trow[2];
        const float A0s = trow[3], A1s = trow[4];

        const float a1 = fmaf(spx, A0, fmaf(spy, A1, cc));
        const float e  = __builtin_amdgcn_exp2f(a1 * 2.88539008f);
        const float h1 = fmaf(-2.f, __builtin_amdgcn_rcpf(e + 1.f), 1.f);
        const float t1 = fmaf(-h1, h1, 1.f);
        const float m2 = -2.f * h1 * t1;
        const float g1x = t1 * A0, g1y = t1 * A1;
        const float sxx = m2 * A0s, syy = m2 * A1s;

#pragma unroll
        for (int jj = 0; jj < 16; ++jj) {
            const float w = wbuf[jj];
            a2[jj]  = fmaf(h1,  w, a2[jj]);
            d2x[jj] = fmaf(g1x, w, d2x[jj]);
            d2y[jj] = fmaf(g1y, w, d2y[jj]);
            exx[jj] = fmaf(sxx, w, exx[jj]);
            eyy[jj] = fmaf(syy, w, eyy[jj]);
        }
    }

    float r[13];
#pragma unroll
    for (int i = 0; i < 13; ++i) r[i] = 0.f;
#pragma unroll
    for (int jj = 0; jj < 16; ++jj) {
        const float h2 = fast_tanh(a2[jj]);
        const float t2 = fmaf(-h2, h2, 1.f);
        const float gx = t2 * d2x[jj];
        const float gy = t2 * d2y[jj];
        const float hxx = fmaf(-2.f * h2 * gx, d2x[jj], t2 * exx[jj]);
        const float hyy = fmaf(-2.f * h2 * gy, d2y[jj], t2 * eyy[jj]);
        const int j = j0 + jj;
        const float w30 = W3[j * 3], w31 = W3[j * 3 + 1], w32 = W3[j * 3 + 2]; // uniform
        r[0]  = fmaf(h2, w30, r[0]);   r[1]  = fmaf(h2, w31, r[1]);   r[2] = fmaf(h2, w32, r[2]);
        r[3]  = fmaf(gx, w30, r[3]);   r[4]  = fmaf(gx, w31, r[4]);   r[5] = fmaf(gx, w32, r[5]);
        r[6]  = fmaf(gy, w30, r[6]);   r[7]  = fmaf(gy, w31, r[7]);   r[8] = fmaf(gy, w32, r[8]);
        r[9]  = fmaf(hxx, w30, r[9]);  r[10] = fmaf(hxx, w31, r[10]);
        r[11] = fmaf(hyy, w30, r[11]); r[12] = fmaf(hyy, w31, r[12]);
    }

    // cross-wave reduction: part[wv][lane][i], stride 13 floats per lane
    __shared__ float part[8][64][13];
#pragma unroll
    for (int i = 0; i < 13; ++i) part[wv][lane][i] = r[i];
    __syncthreads();

    if (tid < 64) {
        const int pl = tid;
        float s[13];
#pragma unroll
        for (int i = 0; i < 13; ++i) {
            float acc = part[0][pl][i];
#pragma unroll
            for (int w = 1; w < 8; ++w) acc += part[w][pl][i];
            s[i] = acc;
        }
        const int p2 = blockIdx.x * 64 + pl;
        const float u = s[0], v = s[1], pp = s[2];
        const float ux = s[3], vx = s[4], px = s[5];
        const float uy = s[6], vy = s[7], py = s[8];
        const float uxx = s[9], vxx = s[10], uyy = s[11], vyy = s[12];
        if (p2 < NDOM) {
            out[CONT_OFF + p2] = ux + vy;
            out[MOMX_OFF + p2] = fmaf(u, ux, fmaf(v, uy, px)) - (uxx + uyy) * INV_RE;
            out[MOMY_OFF + p2] = fmaf(u, vx, fmaf(v, vy, py)) - (vxx + vyy) * INV_RE;
        } else {
            const int i = p2 - NDOM;
            const int idx = bidx[i];
            const float* xbp = x + (size_t)idx * DXI;
            const float* mm = xmask + (size_t)idx * 6;
            const float tx = xbp[0], ty = xbp[1];
            const float nx = -ty, ny = tx;
            const float r_vt = fabsf(tx * u + ty * v - xbp[2]) * mm[1];
            const float r_vn = fabsf(nx * u + ny * v - xbp[3]) * mm[2];
            const float r_p  = fabsf(pp - xbp[4]) * mm[3];
            const float r_dv = fabsf(nx * ux + ny * vy - xbp[5]) * mm[4];
            const float r_dp = fabsf(nx * px + ny * py - xbp[6]) * mm[5];
            const float c = mm[1] + mm[2] + mm[3] + mm[4] + mm[5];
            out[BND_OFF + i] = (r_vt + r_vn + r_p + r_dv + r_dp) / c;
        }
    }
}

extern "C" void kernel_launch(void* const* d_in, const int* in_sizes, int n_in,
                              void* d_out, int out_size, void* d_ws, size_t ws_size,
                              hipStream_t stream) {
    const float* x     = (const float*)d_in[0];
    const float* xmask = (const float*)d_in[1];
    const int*   eidx  = (const int*)d_in[2];
    const float* eattr = (const float*)d_in[3];
    const float* pos   = (const float*)d_in[4];
    const float* dom   = (const float*)d_in[6];
    const float* bnd   = (const float*)d_in[7];
    const int*   bidx  = (const int*)d_in[8];
    const float* Wx    = (const float*)d_in[9];
    const float* Wp    = (const float*)d_in[10];
    const float* We    = (const float*)d_in[11];
    const float* Wout  = (const float*)d_in[12];
    const float* W1    = (const float*)d_in[13];
    const float* b1    = (const float*)d_in[14];
    const float* W2    = (const float*)d_in[15];
    const float* b2    = (const float*)d_in[16];
    const float* W3    = (const float*)d_in[17];

    float* out = (float*)d_out;

    // workspace layout (16B-aligned sections): total ~46.5 MB
    int*      counts   = (int*)d_ws;                    // NNODES
    int*      offsets  = counts + NNODES;               // NNODES + 8
    int*      cursor   = offsets + NNODES + 8;          // NNODES
    int*      bsum     = cursor + NNODES;               // 128
    uint4*    csrE     = (uint4*)(bsum + 128);          // NEDGES (16 MB)
    uint4*    xb       = (uint4*)(csrE + NEDGES);       // NNODES*2 (3.2 MB)
    unsigned* agg      = (unsigned*)(xb + (size_t)NNODES * 2); // NNODES*64 (25.6 MB)
    float*    ctx_part = (float*)(agg + (size_t)NNODES * 64);  // NODE_BLOCKS*H (512 KB)
    float*    tab      = ctx_part + (size_t)NODE_BLOCKS * H;   // H*8

    (void)hipMemsetAsync(counts, 0, (size_t)NNODES * sizeof(int), stream);
    (void)hipMemsetAsync(agg, 0, (size_t)NNODES * 64 * sizeof(unsigned), stream);

    hist_pack_kernel<<<512, 256, 0, stream>>>(eidx, x, pos, counts, xb);
    scan1_kernel<<<NSB, 256, 0, stream>>>(counts, offsets, bsum);
    scan2_kernel<<<1, 128, 0, stream>>>(bsum);
    scan3_kernel<<<NSB, 256, 0, stream>>>(offsets, cursor, bsum);
    scatter_kernel<<<512, 256, 0, stream>>>(eidx, eattr, cursor, csrE);
    seg_edge_kernel<<<(NRUNS + 3) / 4, 256, 0, stream>>>(csrE, xb, We, Wx, Wp, agg);
    node_kernel<<<NODE_BLOCKS, 256, 0, stream>>>(x, pos, agg, Wx, Wp, Wout, out, ctx_part);
    ctx_kernel<<<1, H, 0, stream>>>(ctx_part, W1, b1, tab);
    samp_kernel<<<NPTS / 64, 512, 0, stream>>>(dom, bnd, bidx, x, xmask, tab, W2, b2, W3, out);
}

// Round 12
// 345.359 us; speedup vs baseline: 1.4374x; 1.0715x over previous
//
#include <hip/hip_runtime.h>
#include <math.h>

#define H 128
#define DXI 8
#define NNODES 100000
#define NEDGES 1000000
#define NRUNS (NEDGES / 64)
#define NDOM 32768
#define NBND 8192
#define NPTS (NDOM + NBND)
#define INV_RE 1.45e-05f
#define NODE_BLOCKS 1024

#define NSB ((NNODES + 1023) / 1024)   // scan blocks (1024 elems each) = 98

// d_out layout (floats): out_sup[300000] | continuity[32768] | momx[32768] | momy[32768] | boundary[8192]
#define CONT_OFF (NNODES * 3)
#define MOMX_OFF (CONT_OFF + NDOM)
#define MOMY_OFF (MOMX_OFF + NDOM)
#define BND_OFF  (MOMY_OFF + NDOM)

// fast tanh: 1 - 2/(exp2(2x*log2e)+1). Saturates correctly at +/-inf.
__device__ __forceinline__ float fast_tanh(float x) {
    const float e = __builtin_amdgcn_exp2f(x * 2.88539008f);
    return fmaf(-2.f, __builtin_amdgcn_rcpf(e + 1.f), 1.f);
}

// pack two floats to bf16 pair (RNE), low word = a, high word = b
__device__ __forceinline__ unsigned pack_bf16(float a, float b) {
    unsigned ua = __float_as_uint(a), ub = __float_as_uint(b);
    ua += 0x7fffu + ((ua >> 16) & 1u);
    ub += 0x7fffu + ((ub >> 16) & 1u);
    return (ua >> 16) | (ub & 0xffff0000u);
}

// ---------------------------------------------------------------------------
// Histogram of destination nodes (L2-resident int atomics).
// ---------------------------------------------------------------------------
__global__ __launch_bounds__(256) void hist_kernel(
    const int* __restrict__ eidx, int* __restrict__ counts)
{
    const int* dst = eidx + NEDGES;
    for (int e = blockIdx.x * 256 + threadIdx.x; e < NEDGES; e += gridDim.x * 256)
        atomicAdd(&counts[dst[e]], 1);
}

// ---------------------------------------------------------------------------
// th table: th[n][ch-pair lane] = bf16x2( tanh(x@Wx + pos@Wp) ).
// Wave per node, lane owns channels {2l, 2l+1}. 25.6 MB, L3-resident.
// ---------------------------------------------------------------------------
__global__ __launch_bounds__(256) void th_kernel(
    const float* __restrict__ x, const float* __restrict__ pos,
    const float* __restrict__ Wx, const float* __restrict__ Wp,
    unsigned* __restrict__ th)
{
    const int lane = threadIdx.x & 63;
    const int wv   = threadIdx.x >> 6;
    const int c0 = lane * 2, c1 = c0 + 1;

    float wxa[DXI], wxb_[DXI];
#pragma unroll
    for (int k = 0; k < DXI; ++k) { wxa[k] = Wx[k * H + c0]; wxb_[k] = Wx[k * H + c1]; }
    const float wp00 = Wp[c0], wp01 = Wp[H + c0];
    const float wp10 = Wp[c1], wp11 = Wp[H + c1];

    for (int n = blockIdx.x * 4 + wv; n < NNODES; n += gridDim.x * 4) {
        const float* xr = x + (size_t)n * DXI;
        const float px = pos[(size_t)n * 3], py = pos[(size_t)n * 3 + 1];
        float a0 = fmaf(wp00, px, wp01 * py);
        float a1 = fmaf(wp10, px, wp11 * py);
#pragma unroll
        for (int k = 0; k < DXI; ++k) {
            const float xv = xr[k];
            a0 = fmaf(xv, wxa[k], a0);
            a1 = fmaf(xv, wxb_[k], a1);
        }
        th[(size_t)n * 64 + lane] = pack_bf16(fast_tanh(a0), fast_tanh(a1));
    }
}

// ---------------------------------------------------------------------------
// CSR build pass 2a: per-block exclusive scan (1024 elems/block).
// ---------------------------------------------------------------------------
__global__ __launch_bounds__(256) void scan1_kernel(
    const int* __restrict__ counts, int* __restrict__ excl, int* __restrict__ bsum)
{
    const int tid = threadIdx.x, b = blockIdx.x;
    const int base = b * 1024 + tid * 4;
    int v0 = 0, v1 = 0, v2 = 0, v3 = 0;
    if (base + 3 < NNODES) {
        const int4 t = *(const int4*)(counts + base);
        v0 = t.x; v1 = t.y; v2 = t.z; v3 = t.w;
    } else {
        if (base     < NNODES) v0 = counts[base];
        if (base + 1 < NNODES) v1 = counts[base + 1];
        if (base + 2 < NNODES) v2 = counts[base + 2];
        if (base + 3 < NNODES) v3 = counts[base + 3];
    }
    const int own = v0 + v1 + v2 + v3;
    int s = own;
    const int lane = tid & 63, wv = tid >> 6;
#pragma unroll
    for (int d = 1; d < 64; d <<= 1) {
        const int t = __shfl_up(s, d);
        if (lane >= d) s += t;
    }
    __shared__ int wsum[4];
    if (lane == 63) wsum[wv] = s;
    __syncthreads();
    int woff = 0;
    for (int w = 0; w < wv; ++w) woff += wsum[w];
    const int e0 = s - own + woff;
    const int e1 = e0 + v0, e2 = e1 + v1, e3 = e2 + v2;
    if (base + 3 < NNODES) {
        *(int4*)(excl + base) = make_int4(e0, e1, e2, e3);
    } else {
        if (base     < NNODES) excl[base]     = e0;
        if (base + 1 < NNODES) excl[base + 1] = e1;
        if (base + 2 < NNODES) excl[base + 2] = e2;
        if (base + 3 < NNODES) excl[base + 3] = e3;
    }
    if (tid == 0) bsum[b] = wsum[0] + wsum[1] + wsum[2] + wsum[3];
}

// ---------------------------------------------------------------------------
// CSR build pass 2b: exclusive scan of block totals (1 block).
// ---------------------------------------------------------------------------
__global__ __launch_bounds__(128) void scan2_kernel(int* __restrict__ bsum)
{
    const int tid = threadIdx.x;
    int v = (tid < NSB) ? bsum[tid] : 0;
    const int own = v;
    const int lane = tid & 63, wv = tid >> 6;
#pragma unroll
    for (int d = 1; d < 64; d <<= 1) {
        const int t = __shfl_up(v, d);
        if (lane >= d) v += t;
    }
    __shared__ int ws2[2];
    if (lane == 63) ws2[wv] = v;
    __syncthreads();
    if (wv == 1) v += ws2[0];
    if (tid < NSB) bsum[tid] = v - own;
}

// ---------------------------------------------------------------------------
// CSR build pass 2c: add block offsets; produce cursor[].
// ---------------------------------------------------------------------------
__global__ __launch_bounds__(256) void scan3_kernel(
    int* __restrict__ offsets, int* __restrict__ cursor, const int* __restrict__ bsum)
{
    const int tid = threadIdx.x, b = blockIdx.x;
    const int base = b * 1024 + tid * 4;
    const int add = bsum[b];
    if (base + 3 < NNODES) {
        int4 t = *(const int4*)(offsets + base);
        t.x += add; t.y += add; t.z += add; t.w += add;
        *(int4*)(offsets + base) = t;
        *(int4*)(cursor + base) = t;
    } else {
        for (int i = 0; i < 4; ++i)
            if (base + i < NNODES) {
                const int t = offsets[base + i] + add;
                offsets[base + i] = t;
                cursor[base + i] = t;
            }
    }
}

// ---------------------------------------------------------------------------
// CSR build pass 3: scatter self-contained edge records into dst-sorted
// order:  uint4{ src, dst, bf16(e0,e1), bf16(e3, 0) }  (one 16B store).
// ---------------------------------------------------------------------------
__global__ __launch_bounds__(256) void scatter_kernel(
    const int* __restrict__ eidx, const float* __restrict__ eattr,
    int* __restrict__ cursor, uint4* __restrict__ csrE)
{
    const int* dst = eidx + NEDGES;
    for (int e = blockIdx.x * 256 + threadIdx.x; e < NEDGES; e += gridDim.x * 256) {
        const int d = dst[e];
        const float4 ea = ((const float4*)eattr)[e];
        const int slot = atomicAdd(&cursor[d], 1);
        uint4 r;
        r.x = (unsigned)eidx[e];
        r.y = (unsigned)d;
        r.z = pack_bf16(ea.x, ea.y);
        r.w = pack_bf16(ea.w, 0.f);
        csrE[slot] = r;
    }
}

// ---------------------------------------------------------------------------
// Segmented edge kernel v2: one WAVE per 64-edge dst-sorted run.
// Per edge: one COALESCED 256B th-row read (precomputed tanh — no MLP, no
// tanh here), issued in 16-deep batches for MLP; ea/dst broadcast via
// readlane; flush to agg[dst] on dst change (plain store interior, CAS at
// run boundaries).
// ---------------------------------------------------------------------------
__global__ __launch_bounds__(256) void seg_edge_kernel(
    const uint4* __restrict__ csrE, const unsigned* __restrict__ th,
    const float* __restrict__ We, unsigned* __restrict__ agg)
{
    const int run = blockIdx.x * 4 + (threadIdx.x >> 6);
    if (run >= NRUNS) return;
    const int lane = threadIdx.x & 63;
    const int c0 = lane * 2, c1 = c0 + 1;

    const float wea0 = We[c0], wea1 = We[H + c0], wea2 = We[2 * H + c0];
    const float web0 = We[c1], web1 = We[H + c1], web2 = We[2 * H + c1];

    const uint4 rec = csrE[(size_t)run * 64 + lane];
    const int mydst = (int)rec.y;

    float acc0 = 0.f, acc1 = 0.f;
    bool first = true;
    int cur = __builtin_amdgcn_readlane(mydst, 0);

#pragma unroll
    for (int sub = 0; sub < 4; ++sub) {
        // issue 16 coalesced th-row loads (16 in flight, one wait)
        unsigned rowv[16];
#pragma unroll
        for (int t = 0; t < 16; ++t) {
            const int s = __builtin_amdgcn_readlane((int)rec.x, sub * 16 + t);
            rowv[t] = th[(size_t)s * 64 + lane];
        }
#pragma unroll
        for (int t = 0; t < 16; ++t) {
            const int e = sub * 16 + t;
            const unsigned ue01 = (unsigned)__builtin_amdgcn_readlane((int)rec.z, e);
            const unsigned ue3  = (unsigned)__builtin_amdgcn_readlane((int)rec.w, e);
            const float e0f = __uint_as_float(ue01 << 16);
            const float e1f = __uint_as_float(ue01 & 0xffff0000u);
            const float e3f = __uint_as_float(ue3 << 16);
            const float th0 = __uint_as_float(rowv[t] << 16);
            const float th1 = __uint_as_float(rowv[t] & 0xffff0000u);
            const float w0 = fmaf(e0f, wea0, fmaf(e1f, wea1, e3f * wea2));
            const float w1 = fmaf(e0f, web0, fmaf(e1f, web1, e3f * web2));
            acc0 = fmaf(th0, w0, acc0);
            acc1 = fmaf(th1, w1, acc1);

            const int nxt = (e < 63) ? __builtin_amdgcn_readlane(mydst, e + 1) : -1;
            if (nxt != cur) {
                unsigned* p = agg + (size_t)cur * 64 + lane;
                if (first || e == 63) {
                    unsigned old = *p;
                    while (true) {
                        const float g0 = __uint_as_float(old << 16) + acc0;
                        const float g1 = __uint_as_float(old & 0xffff0000u) + acc1;
                        const unsigned nw = pack_bf16(g0, g1);
                        const unsigned prev = atomicCAS(p, old, nw);
                        if (prev == old) break;
                        old = prev;
                    }
                } else {
                    *p = pack_bf16(acc0, acc1);
                }
                acc0 = 0.f; acc1 = 0.f;
                first = false;
                cur = nxt;
            }
        }
    }
}

// ---------------------------------------------------------------------------
// Node kernel: wave per node, 2ch/lane. ctx via LDS reduce + per-block row.
// ---------------------------------------------------------------------------
__global__ __launch_bounds__(256) void node_kernel(
    const float* __restrict__ x, const float* __restrict__ pos,
    const unsigned* __restrict__ agg,
    const float* __restrict__ Wx, const float* __restrict__ Wp,
    const float* __restrict__ Wout,
    float* __restrict__ out_sup, float* __restrict__ ctx_part)
{
    const int lane = threadIdx.x & 63;
    const int wv   = threadIdx.x >> 6;
    const int c0 = lane * 2, c1 = c0 + 1;

    float wxa[DXI], wxb_[DXI];
#pragma unroll
    for (int k = 0; k < DXI; ++k) { wxa[k] = Wx[k * H + c0]; wxb_[k] = Wx[k * H + c1]; }
    const float wp00 = Wp[c0], wp01 = Wp[H + c0];
    const float wp10 = Wp[c1], wp11 = Wp[H + c1];
    const float woa0 = Wout[c0 * 3], woa1 = Wout[c0 * 3 + 1], woa2 = Wout[c0 * 3 + 2];
    const float wob0 = Wout[c1 * 3], wob1 = Wout[c1 * 3 + 1], wob2 = Wout[c1 * 3 + 2];

    float ctx0 = 0.f, ctx1 = 0.f;

    for (int n = blockIdx.x * 4 + wv; n < NNODES; n += gridDim.x * 4) {
        const unsigned ag = agg[(size_t)n * 64 + lane];
        const float* xr = x + (size_t)n * DXI;
        const float px = pos[(size_t)n * 3], py = pos[(size_t)n * 3 + 1];
        float a0 = fmaf(wp00, px, wp01 * py);
        float a1 = fmaf(wp10, px, wp11 * py);
#pragma unroll
        for (int k = 0; k < DXI; ++k) {
            const float xv = xr[k];
            a0 = fmaf(xv, wxa[k], a0);
            a1 = fmaf(xv, wxb_[k], a1);
        }
        const float h0 = fast_tanh(fast_tanh(a0) + __uint_as_float(ag << 16));
        const float h1 = fast_tanh(fast_tanh(a1) + __uint_as_float(ag & 0xffff0000u));
        ctx0 += h0; ctx1 += h1;

        float p0 = fmaf(h0, woa0, h1 * wob0);
        float p1 = fmaf(h0, woa1, h1 * wob1);
        float p2 = fmaf(h0, woa2, h1 * wob2);
#pragma unroll
        for (int m = 32; m; m >>= 1) {
            p0 += __shfl_xor(p0, m);
            p1 += __shfl_xor(p1, m);
            p2 += __shfl_xor(p2, m);
        }
        if (lane == 0) {
            out_sup[(size_t)n * 3 + 0] = p0;
            out_sup[(size_t)n * 3 + 1] = p1;
            out_sup[(size_t)n * 3 + 2] = p2;
        }
    }

    __shared__ float part[4][H];
    part[wv][c0] = ctx0;
    part[wv][c1] = ctx1;
    __syncthreads();
    if (threadIdx.x < H) {
        const int ch = threadIdx.x;
        ctx_part[(size_t)blockIdx.x * H + ch] =
            part[0][ch] + part[1][ch] + part[2][ch] + part[3][ch];
    }
}

// ---------------------------------------------------------------------------
// ctx finalize: sum per-block partial rows, then tab rows.
// ---------------------------------------------------------------------------
__global__ __launch_bounds__(128) void ctx_kernel(
    const float* __restrict__ ctx_part, const float* __restrict__ W1,
    const float* __restrict__ b1, float* __restrict__ tab)
{
    __shared__ float ctx[H];
    const int ch = threadIdx.x;
    float s0 = 0.f, s1 = 0.f, s2 = 0.f, s3 = 0.f;
#pragma unroll 4
    for (int b = 0; b < NODE_BLOCKS; b += 4) {
        s0 += ctx_part[(size_t)(b + 0) * H + ch];
        s1 += ctx_part[(size_t)(b + 1) * H + ch];
        s2 += ctx_part[(size_t)(b + 2) * H + ch];
        s3 += ctx_part[(size_t)(b + 3) * H + ch];
    }
    ctx[ch] = (s0 + s1 + s2 + s3) * (1.0f / (float)NNODES);
    __syncthreads();
    float acc = b1[ch];
    for (int k = 0; k < H; ++k) acc = fmaf(ctx[k], W1[(size_t)(2 + k) * H + ch], acc);
    const float A0 = W1[ch], A1 = W1[H + ch];
    tab[ch * 8 + 0] = A0;
    tab[ch * 8 + 1] = A1;
    tab[ch * 8 + 2] = acc;
    tab[ch * 8 + 3] = A0 * A0;
    tab[ch * 8 + 4] = A1 * A1;
    tab[ch * 8 + 5] = 0.f;
    tab[ch * 8 + 6] = 0.f;
    tab[ch * 8 + 7] = 0.f;
}

// ---------------------------------------------------------------------------
// Sampling kernel v4: wave-per-j-chunk; all weight accesses wave-uniform
// (scalar pipe); inner loop pure register FMA; LDS cross-wave reduce.
// ---------------------------------------------------------------------------
__global__ __launch_bounds__(512, 2) void samp_kernel(
    const float* __restrict__ dom, const float* __restrict__ bnd,
    const int* __restrict__ bidx,
    const float* __restrict__ x, const float* __restrict__ xmask,
    const float* __restrict__ tab,
    const float* __restrict__ W2, const float* __restrict__ b2,
    const float* __restrict__ W3, float* __restrict__ out)
{
    const int tid  = threadIdx.x;
    const int lane = tid & 63;
    const int wv   = __builtin_amdgcn_readfirstlane(tid >> 6);  // 0..7, uniform
    const int j0   = wv * 16;
    const int p    = blockIdx.x * 64 + lane;

    float spx, spy;
    if (p < NDOM) { spx = dom[(size_t)p * 2];          spy = dom[(size_t)p * 2 + 1]; }
    else          { spx = bnd[(size_t)(p - NDOM) * 2]; spy = bnd[(size_t)(p - NDOM) * 2 + 1]; }

    float a2[16], d2x[16], d2y[16], exx[16], eyy[16];
#pragma unroll
    for (int jj = 0; jj < 16; ++jj) {
        a2[jj] = b2[j0 + jj];          // uniform -> scalar load
        d2x[jj] = 0.f; d2y[jj] = 0.f; exx[jj] = 0.f; eyy[jj] = 0.f;
    }

    for (int k = 0; k < H; ++k) {
        const float* wrow = W2 + (size_t)k * H + j0;   // uniform
        float wbuf[16];
#pragma unroll
        for (int q = 0; q < 16; ++q) wbuf[q] = wrow[q];

        const float* trow = tab + (size_t)k * 8;       // uniform
        const float A0 = trow[0], A1 = trow[1], cc = trow[2];
        const float A0s = trow[3], A1s = trow[4];

        const float a1 = fmaf(spx, A0, fmaf(spy, A1, cc));
        const float e  = __builtin_amdgcn_exp2f(a1 * 2.88539008f);
        const float h1 = fmaf(-2.f, __builtin_amdgcn_rcpf(e + 1.f), 1.f);
        const float t1 = fmaf(-h1, h1, 1.f);
        const float m2 = -2.f * h1 * t1;
        const float g1x = t1 * A0, g1y = t1 * A1;
        const float sxx = m2 * A0s, syy = m2 * A1s;

#pragma unroll
        for (int jj = 0; jj < 16; ++jj) {
            const float w = wbuf[jj];
            a2[jj]  = fmaf(h1,  w, a2[jj]);
            d2x[jj] = fmaf(g1x, w, d2x[jj]);
            d2y[jj] = fmaf(g1y, w, d2y[jj]);
            exx[jj] = fmaf(sxx, w, exx[jj]);
            eyy[jj] = fmaf(syy, w, eyy[jj]);
        }
    }

    float r[13];
#pragma unroll
    for (int i = 0; i < 13; ++i) r[i] = 0.f;
#pragma unroll
    for (int jj = 0; jj < 16; ++jj) {
        const float h2 = fast_tanh(a2[jj]);
        const float t2 = fmaf(-h2, h2, 1.f);
        const float gx = t2 * d2x[jj];
        const float gy = t2 * d2y[jj];
        const float hxx = fmaf(-2.f * h2 * gx, d2x[jj], t2 * exx[jj]);
        const float hyy = fmaf(-2.f * h2 * gy, d2y[jj], t2 * eyy[jj]);
        const int j = j0 + jj;
        const float w30 = W3[j * 3], w31 = W3[j * 3 + 1], w32 = W3[j * 3 + 2]; // uniform
        r[0]  = fmaf(h2, w30, r[0]);   r[1]  = fmaf(h2, w31, r[1]);   r[2] = fmaf(h2, w32, r[2]);
        r[3]  = fmaf(gx, w30, r[3]);   r[4]  = fmaf(gx, w31, r[4]);   r[5] = fmaf(gx, w32, r[5]);
        r[6]  = fmaf(gy, w30, r[6]);   r[7]  = fmaf(gy, w31, r[7]);   r[8] = fmaf(gy, w32, r[8]);
        r[9]  = fmaf(hxx, w30, r[9]);  r[10] = fmaf(hxx, w31, r[10]);
        r[11] = fmaf(hyy, w30, r[11]); r[12] = fmaf(hyy, w31, r[12]);
    }

    __shared__ float part[8][64][13];
#pragma unroll
    for (int i = 0; i < 13; ++i) part[wv][lane][i] = r[i];
    __syncthreads();

    if (tid < 64) {
        const int pl = tid;
        float s[13];
#pragma unroll
        for (int i = 0; i < 13; ++i) {
            float acc = part[0][pl][i];
#pragma unroll
            for (int w = 1; w < 8; ++w) acc += part[w][pl][i];
            s[i] = acc;
        }
        const int p2 = blockIdx.x * 64 + pl;
        const float u = s[0], v = s[1], pp = s[2];
        const float ux = s[3], vx = s[4], px = s[5];
        const float uy = s[6], vy = s[7], py = s[8];
        const float uxx = s[9], vxx = s[10], uyy = s[11], vyy = s[12];
        if (p2 < NDOM) {
            out[CONT_OFF + p2] = ux + vy;
            out[MOMX_OFF + p2] = fmaf(u, ux, fmaf(v, uy, px)) - (uxx + uyy) * INV_RE;
            out[MOMY_OFF + p2] = fmaf(u, vx, fmaf(v, vy, py)) - (vxx + vyy) * INV_RE;
        } else {
            const int i = p2 - NDOM;
            const int idx = bidx[i];
            const float* xbp = x + (size_t)idx * DXI;
            const float* mm = xmask + (size_t)idx * 6;
            const float tx = xbp[0], ty = xbp[1];
            const float nx = -ty, ny = tx;
            const float r_vt = fabsf(tx * u + ty * v - xbp[2]) * mm[1];
            const float r_vn = fabsf(nx * u + ny * v - xbp[3]) * mm[2];
            const float r_p  = fabsf(pp - xbp[4]) * mm[3];
            const float r_dv = fabsf(nx * ux + ny * vy - xbp[5]) * mm[4];
            const float r_dp = fabsf(nx * px + ny * py - xbp[6]) * mm[5];
            const float c = mm[1] + mm[2] + mm[3] + mm[4] + mm[5];
            out[BND_OFF + i] = (r_vt + r_vn + r_p + r_dv + r_dp) / c;
        }
    }
}

extern "C" void kernel_launch(void* const* d_in, const int* in_sizes, int n_in,
                              void* d_out, int out_size, void* d_ws, size_t ws_size,
                              hipStream_t stream) {
    const float* x     = (const float*)d_in[0];
    const float* xmask = (const float*)d_in[1];
    const int*   eidx  = (const int*)d_in[2];
    const float* eattr = (const float*)d_in[3];
    const float* pos   = (const float*)d_in[4];
    const float* dom   = (const float*)d_in[6];
    const float* bnd   = (const float*)d_in[7];
    const int*   bidx  = (const int*)d_in[8];
    const float* Wx    = (const float*)d_in[9];
    const float* Wp    = (const float*)d_in[10];
    const float* We    = (const float*)d_in[11];
    const float* Wout  = (const float*)d_in[12];
    const float* W1    = (const float*)d_in[13];
    const float* b1    = (const float*)d_in[14];
    const float* W2    = (const float*)d_in[15];
    const float* b2    = (const float*)d_in[16];
    const float* W3    = (const float*)d_in[17];

    float* out = (float*)d_out;

    // workspace layout (16B-aligned sections): total ~68.9 MB
    int*      counts   = (int*)d_ws;                    // NNODES
    int*      offsets  = counts + NNODES;               // NNODES + 8
    int*      cursor   = offsets + NNODES + 8;          // NNODES
    int*      bsum     = cursor + NNODES;               // 128
    uint4*    csrE     = (uint4*)(bsum + 128);          // NEDGES (16 MB)
    unsigned* th       = (unsigned*)(csrE + NEDGES);    // NNODES*64 (25.6 MB)
    unsigned* agg      = th + (size_t)NNODES * 64;      // NNODES*64 (25.6 MB)
    float*    ctx_part = (float*)(agg + (size_t)NNODES * 64); // NODE_BLOCKS*H (512 KB)
    float*    tab      = ctx_part + (size_t)NODE_BLOCKS * H;  // H*8

    (void)hipMemsetAsync(counts, 0, (size_t)NNODES * sizeof(int), stream);
    (void)hipMemsetAsync(agg, 0, (size_t)NNODES * 64 * sizeof(unsigned), stream);

    hist_kernel<<<512, 256, 0, stream>>>(eidx, counts);
    th_kernel<<<1024, 256, 0, stream>>>(x, pos, Wx, Wp, th);
    scan1_kernel<<<NSB, 256, 0, stream>>>(counts, offsets, bsum);
    scan2_kernel<<<1, 128, 0, stream>>>(bsum);
    scan3_kernel<<<NSB, 256, 0, stream>>>(offsets, cursor, bsum);
    scatter_kernel<<<512, 256, 0, stream>>>(eidx, eattr, cursor, csrE);
    seg_edge_kernel<<<(NRUNS + 3) / 4, 256, 0, stream>>>(csrE, th, We, agg);
    node_kernel<<<NODE_BLOCKS, 256, 0, stream>>>(x, pos, agg, Wx, Wp, Wout, out, ctx_part);
    ctx_kernel<<<1, H, 0, stream>>>(ctx_part, W1, b1, tab);
    samp_kernel<<<NPTS / 64, 512, 0, stream>>>(dom, bnd, bidx, x, xmask, tab, W2, b2, W3, out);
}

// Round 13
// 343.316 us; speedup vs baseline: 1.4460x; 1.0059x over previous
//
#include <hip/hip_runtime.h>
#include <math.h>

#define H 128
#define DXI 8
#define NNODES 100000
#define NEDGES 1000000
#define NRUNS (NEDGES / 64)
#define NDOM 32768
#define NBND 8192
#define NPTS (NDOM + NBND)
#define INV_RE 1.45e-05f
#define NODE_BLOCKS 1024

#define NSB ((NNODES + 1023) / 1024)   // scan blocks (1024 elems each) = 98

// d_out layout (floats): out_sup[300000] | continuity[32768] | momx[32768] | momy[32768] | boundary[8192]
#define CONT_OFF (NNODES * 3)
#define MOMX_OFF (CONT_OFF + NDOM)
#define MOMY_OFF (MOMX_OFF + NDOM)
#define BND_OFF  (MOMY_OFF + NDOM)

// fast tanh: 1 - 2/(exp2(2x*log2e)+1). Saturates correctly at +/-inf.
__device__ __forceinline__ float fast_tanh(float x) {
    const float e = __builtin_amdgcn_exp2f(x * 2.88539008f);
    return fmaf(-2.f, __builtin_amdgcn_rcpf(e + 1.f), 1.f);
}

// pack two floats to bf16 pair (RNE), low word = a, high word = b
__device__ __forceinline__ unsigned pack_bf16(float a, float b) {
    unsigned ua = __float_as_uint(a), ub = __float_as_uint(b);
    ua += 0x7fffu + ((ua >> 16) & 1u);
    ub += 0x7fffu + ((ub >> 16) & 1u);
    return (ua >> 16) | (ub & 0xffff0000u);
}

// ---------------------------------------------------------------------------
// th table + dst histogram (fused). th[n][lane] = bf16x2(tanh(x@Wx+pos@Wp)),
// wave per node, lane owns channels {2l,2l+1}. Then thread-per-edge hist.
// ---------------------------------------------------------------------------
__global__ __launch_bounds__(256) void hist_th_kernel(
    const int* __restrict__ eidx, const float* __restrict__ x,
    const float* __restrict__ pos,
    const float* __restrict__ Wx, const float* __restrict__ Wp,
    int* __restrict__ counts, unsigned* __restrict__ th)
{
    const int lane = threadIdx.x & 63;
    const int wv   = threadIdx.x >> 6;
    const int c0 = lane * 2, c1 = c0 + 1;

    float wxa[DXI], wxb_[DXI];
#pragma unroll
    for (int k = 0; k < DXI; ++k) { wxa[k] = Wx[k * H + c0]; wxb_[k] = Wx[k * H + c1]; }
    const float wp00 = Wp[c0], wp01 = Wp[H + c0];
    const float wp10 = Wp[c1], wp11 = Wp[H + c1];

    for (int n = blockIdx.x * 4 + wv; n < NNODES; n += gridDim.x * 4) {
        const float* xr = x + (size_t)n * DXI;
        const float px = pos[(size_t)n * 3], py = pos[(size_t)n * 3 + 1];
        float a0 = fmaf(wp00, px, wp01 * py);
        float a1 = fmaf(wp10, px, wp11 * py);
#pragma unroll
        for (int k = 0; k < DXI; ++k) {
            const float xv = xr[k];
            a0 = fmaf(xv, wxa[k], a0);
            a1 = fmaf(xv, wxb_[k], a1);
        }
        th[(size_t)n * 64 + lane] = pack_bf16(fast_tanh(a0), fast_tanh(a1));
    }

    const int* dst = eidx + NEDGES;
    for (int e = blockIdx.x * 256 + threadIdx.x; e < NEDGES; e += gridDim.x * 256)
        atomicAdd(&counts[dst[e]], 1);
}

// ---------------------------------------------------------------------------
// CSR build pass 2a: per-block exclusive scan (1024 elems/block).
// ---------------------------------------------------------------------------
__global__ __launch_bounds__(256) void scan1_kernel(
    const int* __restrict__ counts, int* __restrict__ excl, int* __restrict__ bsum)
{
    const int tid = threadIdx.x, b = blockIdx.x;
    const int base = b * 1024 + tid * 4;
    int v0 = 0, v1 = 0, v2 = 0, v3 = 0;
    if (base + 3 < NNODES) {
        const int4 t = *(const int4*)(counts + base);
        v0 = t.x; v1 = t.y; v2 = t.z; v3 = t.w;
    } else {
        if (base     < NNODES) v0 = counts[base];
        if (base + 1 < NNODES) v1 = counts[base + 1];
        if (base + 2 < NNODES) v2 = counts[base + 2];
        if (base + 3 < NNODES) v3 = counts[base + 3];
    }
    const int own = v0 + v1 + v2 + v3;
    int s = own;
    const int lane = tid & 63, wv = tid >> 6;
#pragma unroll
    for (int d = 1; d < 64; d <<= 1) {
        const int t = __shfl_up(s, d);
        if (lane >= d) s += t;
    }
    __shared__ int wsum[4];
    if (lane == 63) wsum[wv] = s;
    __syncthreads();
    int woff = 0;
    for (int w = 0; w < wv; ++w) woff += wsum[w];
    const int e0 = s - own + woff;
    const int e1 = e0 + v0, e2 = e1 + v1, e3 = e2 + v2;
    if (base + 3 < NNODES) {
        *(int4*)(excl + base) = make_int4(e0, e1, e2, e3);
    } else {
        if (base     < NNODES) excl[base]     = e0;
        if (base + 1 < NNODES) excl[base + 1] = e1;
        if (base + 2 < NNODES) excl[base + 2] = e2;
        if (base + 3 < NNODES) excl[base + 3] = e3;
    }
    if (tid == 0) bsum[b] = wsum[0] + wsum[1] + wsum[2] + wsum[3];
}

// ---------------------------------------------------------------------------
// CSR build pass 2b: exclusive scan of block totals (1 block).
// ---------------------------------------------------------------------------
__global__ __launch_bounds__(128) void scan2_kernel(int* __restrict__ bsum)
{
    const int tid = threadIdx.x;
    int v = (tid < NSB) ? bsum[tid] : 0;
    const int own = v;
    const int lane = tid & 63, wv = tid >> 6;
#pragma unroll
    for (int d = 1; d < 64; d <<= 1) {
        const int t = __shfl_up(v, d);
        if (lane >= d) v += t;
    }
    __shared__ int ws2[2];
    if (lane == 63) ws2[wv] = v;
    __syncthreads();
    if (wv == 1) v += ws2[0];
    if (tid < NSB) bsum[tid] = v - own;
}

// ---------------------------------------------------------------------------
// CSR build pass 2c: add block offsets; produce cursor[].
// ---------------------------------------------------------------------------
__global__ __launch_bounds__(256) void scan3_kernel(
    int* __restrict__ offsets, int* __restrict__ cursor, const int* __restrict__ bsum)
{
    const int tid = threadIdx.x, b = blockIdx.x;
    const int base = b * 1024 + tid * 4;
    const int add = bsum[b];
    if (base + 3 < NNODES) {
        int4 t = *(const int4*)(offsets + base);
        t.x += add; t.y += add; t.z += add; t.w += add;
        *(int4*)(offsets + base) = t;
        *(int4*)(cursor + base) = t;
    } else {
        for (int i = 0; i < 4; ++i)
            if (base + i < NNODES) {
                const int t = offsets[base + i] + add;
                offsets[base + i] = t;
                cursor[base + i] = t;
            }
    }
}

// ---------------------------------------------------------------------------
// CSR build pass 3: scatter self-contained edge records into dst-sorted
// order:  uint4{ src, dst, bf16(e0,e1), bf16(e3, 0) }  (one 16B store).
// ---------------------------------------------------------------------------
__global__ __launch_bounds__(256) void scatter_kernel(
    const int* __restrict__ eidx, const float* __restrict__ eattr,
    int* __restrict__ cursor, uint4* __restrict__ csrE)
{
    const int* dst = eidx + NEDGES;
    for (int e = blockIdx.x * 256 + threadIdx.x; e < NEDGES; e += gridDim.x * 256) {
        const int d = dst[e];
        const float4 ea = ((const float4*)eattr)[e];
        const int slot = atomicAdd(&cursor[d], 1);
        uint4 r;
        r.x = (unsigned)eidx[e];
        r.y = (unsigned)d;
        r.z = pack_bf16(ea.x, ea.y);
        r.w = pack_bf16(ea.w, 0.f);
        csrE[slot] = r;
    }
}

// ---------------------------------------------------------------------------
// Segmented edge kernel: one WAVE per 64-edge dst-sorted run. Coalesced
// th-row reads (16-deep batches), readlane broadcast, segmented flush.
// ---------------------------------------------------------------------------
__global__ __launch_bounds__(256) void seg_edge_kernel(
    const uint4* __restrict__ csrE, const unsigned* __restrict__ th,
    const float* __restrict__ We, unsigned* __restrict__ agg)
{
    const int run = blockIdx.x * 4 + (threadIdx.x >> 6);
    if (run >= NRUNS) return;
    const int lane = threadIdx.x & 63;
    const int c0 = lane * 2, c1 = c0 + 1;

    const float wea0 = We[c0], wea1 = We[H + c0], wea2 = We[2 * H + c0];
    const float web0 = We[c1], web1 = We[H + c1], web2 = We[2 * H + c1];

    const uint4 rec = csrE[(size_t)run * 64 + lane];
    const int mydst = (int)rec.y;

    float acc0 = 0.f, acc1 = 0.f;
    bool first = true;
    int cur = __builtin_amdgcn_readlane(mydst, 0);

#pragma unroll
    for (int sub = 0; sub < 4; ++sub) {
        unsigned rowv[16];
#pragma unroll
        for (int t = 0; t < 16; ++t) {
            const int s = __builtin_amdgcn_readlane((int)rec.x, sub * 16 + t);
            rowv[t] = th[(size_t)s * 64 + lane];
        }
#pragma unroll
        for (int t = 0; t < 16; ++t) {
            const int e = sub * 16 + t;
            const unsigned ue01 = (unsigned)__builtin_amdgcn_readlane((int)rec.z, e);
            const unsigned ue3  = (unsigned)__builtin_amdgcn_readlane((int)rec.w, e);
            const float e0f = __uint_as_float(ue01 << 16);
            const float e1f = __uint_as_float(ue01 & 0xffff0000u);
            const float e3f = __uint_as_float(ue3 << 16);
            const float th0 = __uint_as_float(rowv[t] << 16);
            const float th1 = __uint_as_float(rowv[t] & 0xffff0000u);
            const float w0 = fmaf(e0f, wea0, fmaf(e1f, wea1, e3f * wea2));
            const float w1 = fmaf(e0f, web0, fmaf(e1f, web1, e3f * web2));
            acc0 = fmaf(th0, w0, acc0);
            acc1 = fmaf(th1, w1, acc1);

            const int nxt = (e < 63) ? __builtin_amdgcn_readlane(mydst, e + 1) : -1;
            if (nxt != cur) {
                unsigned* p = agg + (size_t)cur * 64 + lane;
                if (first || e == 63) {
                    unsigned old = *p;
                    while (true) {
                        const float g0 = __uint_as_float(old << 16) + acc0;
                        const float g1 = __uint_as_float(old & 0xffff0000u) + acc1;
                        const unsigned nw = pack_bf16(g0, g1);
                        const unsigned prev = atomicCAS(p, old, nw);
                        if (prev == old) break;
                        old = prev;
                    }
                } else {
                    *p = pack_bf16(acc0, acc1);
                }
                acc0 = 0.f; acc1 = 0.f;
                first = false;
                cur = nxt;
            }
        }
    }
}

// ---------------------------------------------------------------------------
// Node kernel: wave per node, 2ch/lane. ctx via LDS reduce + per-block row.
// ---------------------------------------------------------------------------
__global__ __launch_bounds__(256) void node_kernel(
    const float* __restrict__ x, const float* __restrict__ pos,
    const unsigned* __restrict__ agg,
    const float* __restrict__ Wx, const float* __restrict__ Wp,
    const float* __restrict__ Wout,
    float* __restrict__ out_sup, float* __restrict__ ctx_part)
{
    const int lane = threadIdx.x & 63;
    const int wv   = threadIdx.x >> 6;
    const int c0 = lane * 2, c1 = c0 + 1;

    float wxa[DXI], wxb_[DXI];
#pragma unroll
    for (int k = 0; k < DXI; ++k) { wxa[k] = Wx[k * H + c0]; wxb_[k] = Wx[k * H + c1]; }
    const float wp00 = Wp[c0], wp01 = Wp[H + c0];
    const float wp10 = Wp[c1], wp11 = Wp[H + c1];
    const float woa0 = Wout[c0 * 3], woa1 = Wout[c0 * 3 + 1], woa2 = Wout[c0 * 3 + 2];
    const float wob0 = Wout[c1 * 3], wob1 = Wout[c1 * 3 + 1], wob2 = Wout[c1 * 3 + 2];

    float ctx0 = 0.f, ctx1 = 0.f;

    for (int n = blockIdx.x * 4 + wv; n < NNODES; n += gridDim.x * 4) {
        const unsigned ag = agg[(size_t)n * 64 + lane];
        const float* xr = x + (size_t)n * DXI;
        const float px = pos[(size_t)n * 3], py = pos[(size_t)n * 3 + 1];
        float a0 = fmaf(wp00, px, wp01 * py);
        float a1 = fmaf(wp10, px, wp11 * py);
#pragma unroll
        for (int k = 0; k < DXI; ++k) {
            const float xv = xr[k];
            a0 = fmaf(xv, wxa[k], a0);
            a1 = fmaf(xv, wxb_[k], a1);
        }
        const float h0 = fast_tanh(fast_tanh(a0) + __uint_as_float(ag << 16));
        const float h1 = fast_tanh(fast_tanh(a1) + __uint_as_float(ag & 0xffff0000u));
        ctx0 += h0; ctx1 += h1;

        float p0 = fmaf(h0, woa0, h1 * wob0);
        float p1 = fmaf(h0, woa1, h1 * wob1);
        float p2 = fmaf(h0, woa2, h1 * wob2);
#pragma unroll
        for (int m = 32; m; m >>= 1) {
            p0 += __shfl_xor(p0, m);
            p1 += __shfl_xor(p1, m);
            p2 += __shfl_xor(p2, m);
        }
        if (lane == 0) {
            out_sup[(size_t)n * 3 + 0] = p0;
            out_sup[(size_t)n * 3 + 1] = p1;
            out_sup[(size_t)n * 3 + 2] = p2;
        }
    }

    __shared__ float part[4][H];
    part[wv][c0] = ctx0;
    part[wv][c1] = ctx1;
    __syncthreads();
    if (threadIdx.x < H) {
        const int ch = threadIdx.x;
        ctx_part[(size_t)blockIdx.x * H + ch] =
            part[0][ch] + part[1][ch] + part[2][ch] + part[3][ch];
    }
}

// ---------------------------------------------------------------------------
// ctx finalize: sum per-block partial rows, then tab rows.
// ---------------------------------------------------------------------------
__global__ __launch_bounds__(128) void ctx_kernel(
    const float* __restrict__ ctx_part, const float* __restrict__ W1,
    const float* __restrict__ b1, float* __restrict__ tab)
{
    __shared__ float ctx[H];
    const int ch = threadIdx.x;
    float s0 = 0.f, s1 = 0.f, s2 = 0.f, s3 = 0.f;
#pragma unroll 4
    for (int b = 0; b < NODE_BLOCKS; b += 4) {
        s0 += ctx_part[(size_t)(b + 0) * H + ch];
        s1 += ctx_part[(size_t)(b + 1) * H + ch];
        s2 += ctx_part[(size_t)(b + 2) * H + ch];
        s3 += ctx_part[(size_t)(b + 3) * H + ch];
    }
    ctx[ch] = (s0 + s1 + s2 + s3) * (1.0f / (float)NNODES);
    __syncthreads();
    float acc = b1[ch];
    for (int k = 0; k < H; ++k) acc = fmaf(ctx[k], W1[(size_t)(2 + k) * H + ch], acc);
    const float A0 = W1[ch], A1 = W1[H + ch];
    tab[ch * 8 + 0] = A0;
    tab[ch * 8 + 1] = A1;
    tab[ch * 8 + 2] = acc;
    tab[ch * 8 + 3] = A0 * A0;
    tab[ch * 8 + 4] = A1 * A1;
    tab[ch * 8 + 5] = 0.f;
    tab[ch * 8 + 6] = 0.f;
    tab[ch * 8 + 7] = 0.f;
}

// ---------------------------------------------------------------------------
// Sampling partial kernel: block = 256 thr (4 waves); wave owns an 8-j
// chunk; quarter q = blockIdx&3 selects j-range of 32; lane = point.
// Grid 2560 = exactly 10 blocks/CU (balanced). All weight accesses are
// wave-uniform (scalar pipe); inner loop pure register FMA. The 13 output
// quantities are LINEAR in per-j sums -> quarters store partials (plain
// coalesced stores), tiny epilogue kernel combines + applies nonlinear math.
// ---------------------------------------------------------------------------
__global__ __launch_bounds__(256, 5) void samp_part_kernel(
    const float* __restrict__ dom, const float* __restrict__ bnd,
    const float* __restrict__ tab,
    const float* __restrict__ W2, const float* __restrict__ b2,
    const float* __restrict__ W3, float* __restrict__ sums)
{
    const int tid  = threadIdx.x;
    const int lane = tid & 63;
    const int wv   = __builtin_amdgcn_readfirstlane(tid >> 6);      // 0..3
    const int q    = __builtin_amdgcn_readfirstlane(blockIdx.x & 3);// 0..3
    const int grp  = blockIdx.x >> 2;                               // 0..639
    const int j0   = q * 32 + wv * 8;
    const int p    = grp * 64 + lane;

    float spx, spy;
    if (p < NDOM) { spx = dom[(size_t)p * 2];          spy = dom[(size_t)p * 2 + 1]; }
    else          { spx = bnd[(size_t)(p - NDOM) * 2]; spy = bnd[(size_t)(p - NDOM) * 2 + 1]; }

    float a2[8], d2x[8], d2y[8], exx[8], eyy[8];
#pragma unroll
    for (int jj = 0; jj < 8; ++jj) {
        a2[jj] = b2[j0 + jj];          // uniform -> scalar load
        d2x[jj] = 0.f; d2y[jj] = 0.f; exx[jj] = 0.f; eyy[jj] = 0.f;
    }

    for (int k = 0; k < H; ++k) {
        const float* wrow = W2 + (size_t)k * H + j0;   // uniform
        float wbuf[8];
#pragma unroll
        for (int t = 0; t < 8; ++t) wbuf[t] = wrow[t];

        const float* trow = tab + (size_t)k * 8;       // uniform
        const float A0 = trow[0], A1 = trow[1], cc = trow[2];
        const float A0s = trow[3], A1s = trow[4];

        const float a1 = fmaf(spx, A0, fmaf(spy, A1, cc));
        const float e  = __builtin_amdgcn_exp2f(a1 * 2.88539008f);
        const float h1 = fmaf(-2.f, __builtin_amdgcn_rcpf(e + 1.f), 1.f);
        const float t1 = fmaf(-h1, h1, 1.f);
        const float m2 = -2.f * h1 * t1;
        const float g1x = t1 * A0, g1y = t1 * A1;
        const float sxx = m2 * A0s, syy = m2 * A1s;

#pragma unroll
        for (int jj = 0; jj < 8; ++jj) {
            const float w = wbuf[jj];
            a2[jj]  = fmaf(h1,  w, a2[jj]);
            d2x[jj] = fmaf(g1x, w, d2x[jj]);
            d2y[jj] = fmaf(g1y, w, d2y[jj]);
            exx[jj] = fmaf(sxx, w, exx[jj]);
            eyy[jj] = fmaf(syy, w, eyy[jj]);
        }
    }

    float r[13];
#pragma unroll
    for (int i = 0; i < 13; ++i) r[i] = 0.f;
#pragma unroll
    for (int jj = 0; jj < 8; ++jj) {
        const float h2 = fast_tanh(a2[jj]);
        const float t2 = fmaf(-h2, h2, 1.f);
        const float gx = t2 * d2x[jj];
        const float gy = t2 * d2y[jj];
        const float hxx = fmaf(-2.f * h2 * gx, d2x[jj], t2 * exx[jj]);
        const float hyy = fmaf(-2.f * h2 * gy, d2y[jj], t2 * eyy[jj]);
        const int j = j0 + jj;
        const float w30 = W3[j * 3], w31 = W3[j * 3 + 1], w32 = W3[j * 3 + 2]; // uniform
        r[0]  = fmaf(h2, w30, r[0]);   r[1]  = fmaf(h2, w31, r[1]);   r[2] = fmaf(h2, w32, r[2]);
        r[3]  = fmaf(gx, w30, r[3]);   r[4]  = fmaf(gx, w31, r[4]);   r[5] = fmaf(gx, w32, r[5]);
        r[6]  = fmaf(gy, w30, r[6]);   r[7]  = fmaf(gy, w31, r[7]);   r[8] = fmaf(gy, w32, r[8]);
        r[9]  = fmaf(hxx, w30, r[9]);  r[10] = fmaf(hxx, w31, r[10]);
        r[11] = fmaf(hyy, w30, r[11]); r[12] = fmaf(hyy, w31, r[12]);
    }

    // cross-wave reduction within the quarter
    __shared__ float part[4][64][13];
#pragma unroll
    for (int i = 0; i < 13; ++i) part[wv][lane][i] = r[i];
    __syncthreads();

    if (tid < 64) {
#pragma unroll
        for (int i = 0; i < 13; ++i) {
            const float s = part[0][tid][i] + part[1][tid][i]
                          + part[2][tid][i] + part[3][tid][i];
            sums[((size_t)(q * 13 + i)) * NPTS + grp * 64 + tid] = s; // coalesced
        }
    }
}

// ---------------------------------------------------------------------------
// Sampling epilogue: combine 4 quarter-partials, apply nonlinear physics
// and boundary math. One thread per point.
// ---------------------------------------------------------------------------
__global__ __launch_bounds__(256) void samp_epi_kernel(
    const float* __restrict__ sums, const int* __restrict__ bidx,
    const float* __restrict__ x, const float* __restrict__ xmask,
    float* __restrict__ out)
{
    const int p = blockIdx.x * 256 + threadIdx.x;
    if (p >= NPTS) return;
    float s[13];
#pragma unroll
    for (int i = 0; i < 13; ++i) {
        s[i] = sums[((size_t)(0 * 13 + i)) * NPTS + p]
             + sums[((size_t)(1 * 13 + i)) * NPTS + p]
             + sums[((size_t)(2 * 13 + i)) * NPTS + p]
             + sums[((size_t)(3 * 13 + i)) * NPTS + p];
    }
    const float u = s[0], v = s[1], pp = s[2];
    const float ux = s[3], vx = s[4], px = s[5];
    const float uy = s[6], vy = s[7], py = s[8];
    const float uxx = s[9], vxx = s[10], uyy = s[11], vyy = s[12];
    if (p < NDOM) {
        out[CONT_OFF + p] = ux + vy;
        out[MOMX_OFF + p] = fmaf(u, ux, fmaf(v, uy, px)) - (uxx + uyy) * INV_RE;
        out[MOMY_OFF + p] = fmaf(u, vx, fmaf(v, vy, py)) - (vxx + vyy) * INV_RE;
    } else {
        const int i = p - NDOM;
        const int idx = bidx[i];
        const float* xbp = x + (size_t)idx * DXI;
        const float* mm = xmask + (size_t)idx * 6;
        const float tx = xbp[0], ty = xbp[1];
        const float nx = -ty, ny = tx;
        const float r_vt = fabsf(tx * u + ty * v - xbp[2]) * mm[1];
        const float r_vn = fabsf(nx * u + ny * v - xbp[3]) * mm[2];
        const float r_p  = fabsf(pp - xbp[4]) * mm[3];
        const float r_dv = fabsf(nx * ux + ny * vy - xbp[5]) * mm[4];
        const float r_dp = fabsf(nx * px + ny * py - xbp[6]) * mm[5];
        const float c = mm[1] + mm[2] + mm[3] + mm[4] + mm[5];
        out[BND_OFF + i] = (r_vt + r_vn + r_p + r_dv + r_dp) / c;
    }
}

extern "C" void kernel_launch(void* const* d_in, const int* in_sizes, int n_in,
                              void* d_out, int out_size, void* d_ws, size_t ws_size,
                              hipStream_t stream) {
    const float* x     = (const float*)d_in[0];
    const float* xmask = (const float*)d_in[1];
    const int*   eidx  = (const int*)d_in[2];
    const float* eattr = (const float*)d_in[3];
    const float* pos   = (const float*)d_in[4];
    const float* dom   = (const float*)d_in[6];
    const float* bnd   = (const float*)d_in[7];
    const int*   bidx  = (const int*)d_in[8];
    const float* Wx    = (const float*)d_in[9];
    const float* Wp    = (const float*)d_in[10];
    const float* We    = (const float*)d_in[11];
    const float* Wout  = (const float*)d_in[12];
    const float* W1    = (const float*)d_in[13];
    const float* b1    = (const float*)d_in[14];
    const float* W2    = (const float*)d_in[15];
    const float* b2    = (const float*)d_in[16];
    const float* W3    = (const float*)d_in[17];

    float* out = (float*)d_out;

    // workspace layout (16B-aligned sections): total ~68.9 MB
    int*      counts   = (int*)d_ws;                    // NNODES
    int*      offsets  = counts + NNODES;               // NNODES + 8
    int*      cursor   = offsets + NNODES + 8;          // NNODES
    int*      bsum     = cursor + NNODES;               // 128
    uint4*    csrE     = (uint4*)(bsum + 128);          // NEDGES (16 MB)
    unsigned* th       = (unsigned*)(csrE + NEDGES);    // NNODES*64 (25.6 MB)
    unsigned* agg      = th + (size_t)NNODES * 64;      // NNODES*64 (25.6 MB)
    float*    ctx_part = (float*)(agg + (size_t)NNODES * 64); // NODE_BLOCKS*H (512 KB)
    float*    tab      = ctx_part + (size_t)NODE_BLOCKS * H;  // H*8
    float*    sums     = (float*)th;   // alias: th is dead after seg_edge (8.5 MB used)

    (void)hipMemsetAsync(counts, 0, (size_t)NNODES * sizeof(int), stream);
    (void)hipMemsetAsync(agg, 0, (size_t)NNODES * 64 * sizeof(unsigned), stream);

    hist_th_kernel<<<1024, 256, 0, stream>>>(eidx, x, pos, Wx, Wp, counts, th);
    scan1_kernel<<<NSB, 256, 0, stream>>>(counts, offsets, bsum);
    scan2_kernel<<<1, 128, 0, stream>>>(bsum);
    scan3_kernel<<<NSB, 256, 0, stream>>>(offsets, cursor, bsum);
    scatter_kernel<<<512, 256, 0, stream>>>(eidx, eattr, cursor, csrE);
    seg_edge_kernel<<<(NRUNS + 3) / 4, 256, 0, stream>>>(csrE, th, We, agg);
    node_kernel<<<NODE_BLOCKS, 256, 0, stream>>>(x, pos, agg, Wx, Wp, Wout, out, ctx_part);
    ctx_kernel<<<1, H, 0, stream>>>(ctx_part, W1, b1, tab);
    samp_part_kernel<<<(NPTS / 64) * 4, 256, 0, stream>>>(dom, bnd, tab, W2, b2, W3, sums);
    samp_epi_kernel<<<(NPTS + 255) / 256, 256, 0, stream>>>(sums, bidx, x, xmask, out);
}

// Round 14
// 331.720 us; speedup vs baseline: 1.4965x; 1.0350x over previous
//
#include <hip/hip_runtime.h>
#include <math.h>

#define H 128
#define DXI 8
#define NNODES 100000
#define NEDGES 1000000
#define NRUNS (NEDGES / 64)
#define NDOM 32768
#define NBND 8192
#define NPTS (NDOM + NBND)
#define INV_RE 1.45e-05f
#define NODE_BLOCKS 1024

#define NSB ((NNODES + 1023) / 1024)   // scan blocks (1024 elems each) = 98

// d_out layout (floats): out_sup[300000] | continuity[32768] | momx[32768] | momy[32768] | boundary[8192]
#define CONT_OFF (NNODES * 3)
#define MOMX_OFF (CONT_OFF + NDOM)
#define MOMY_OFF (MOMX_OFF + NDOM)
#define BND_OFF  (MOMY_OFF + NDOM)

// fast tanh: 1 - 2/(exp2(2x*log2e)+1). Saturates correctly at +/-inf.
__device__ __forceinline__ float fast_tanh(float x) {
    const float e = __builtin_amdgcn_exp2f(x * 2.88539008f);
    return fmaf(-2.f, __builtin_amdgcn_rcpf(e + 1.f), 1.f);
}

// pack two floats to bf16 pair (RNE), low word = a, high word = b
__device__ __forceinline__ unsigned pack_bf16(float a, float b) {
    unsigned ua = __float_as_uint(a), ub = __float_as_uint(b);
    ua += 0x7fffu + ((ua >> 16) & 1u);
    ub += 0x7fffu + ((ub >> 16) & 1u);
    return (ua >> 16) | (ub & 0xffff0000u);
}

// ---------------------------------------------------------------------------
// th table + dst histogram + agg zero-init (fused).
// th[n][lane] = bf16x2(tanh(x@Wx+pos@Wp)), wave per node.
// ---------------------------------------------------------------------------
__global__ __launch_bounds__(256) void hist_th_kernel(
    const int* __restrict__ eidx, const float* __restrict__ x,
    const float* __restrict__ pos,
    const float* __restrict__ Wx, const float* __restrict__ Wp,
    int* __restrict__ counts, unsigned* __restrict__ th,
    uint4* __restrict__ agg4)
{
    const int lane = threadIdx.x & 63;
    const int wv   = threadIdx.x >> 6;
    const int c0 = lane * 2, c1 = c0 + 1;

    // zero agg (overlapped with compute below)
    const int gid = blockIdx.x * 256 + threadIdx.x;
    const uint4 z = make_uint4(0u, 0u, 0u, 0u);
    for (size_t i = gid; i < (size_t)NNODES * 16; i += (size_t)gridDim.x * 256)
        agg4[i] = z;

    float wxa[DXI], wxb_[DXI];
#pragma unroll
    for (int k = 0; k < DXI; ++k) { wxa[k] = Wx[k * H + c0]; wxb_[k] = Wx[k * H + c1]; }
    const float wp00 = Wp[c0], wp01 = Wp[H + c0];
    const float wp10 = Wp[c1], wp11 = Wp[H + c1];

    for (int n = blockIdx.x * 4 + wv; n < NNODES; n += gridDim.x * 4) {
        const float* xr = x + (size_t)n * DXI;
        const float px = pos[(size_t)n * 3], py = pos[(size_t)n * 3 + 1];
        float a0 = fmaf(wp00, px, wp01 * py);
        float a1 = fmaf(wp10, px, wp11 * py);
#pragma unroll
        for (int k = 0; k < DXI; ++k) {
            const float xv = xr[k];
            a0 = fmaf(xv, wxa[k], a0);
            a1 = fmaf(xv, wxb_[k], a1);
        }
        th[(size_t)n * 64 + lane] = pack_bf16(fast_tanh(a0), fast_tanh(a1));
    }

    const int* dst = eidx + NEDGES;
    for (int e = gid; e < NEDGES; e += gridDim.x * 256)
        atomicAdd(&counts[dst[e]], 1);
}

// ---------------------------------------------------------------------------
// CSR build pass 2a: per-block exclusive scan (1024 elems/block).
// ---------------------------------------------------------------------------
__global__ __launch_bounds__(256) void scan1_kernel(
    const int* __restrict__ counts, int* __restrict__ excl, int* __restrict__ bsum)
{
    const int tid = threadIdx.x, b = blockIdx.x;
    const int base = b * 1024 + tid * 4;
    int v0 = 0, v1 = 0, v2 = 0, v3 = 0;
    if (base + 3 < NNODES) {
        const int4 t = *(const int4*)(counts + base);
        v0 = t.x; v1 = t.y; v2 = t.z; v3 = t.w;
    } else {
        if (base     < NNODES) v0 = counts[base];
        if (base + 1 < NNODES) v1 = counts[base + 1];
        if (base + 2 < NNODES) v2 = counts[base + 2];
        if (base + 3 < NNODES) v3 = counts[base + 3];
    }
    const int own = v0 + v1 + v2 + v3;
    int s = own;
    const int lane = tid & 63, wv = tid >> 6;
#pragma unroll
    for (int d = 1; d < 64; d <<= 1) {
        const int t = __shfl_up(s, d);
        if (lane >= d) s += t;
    }
    __shared__ int wsum[4];
    if (lane == 63) wsum[wv] = s;
    __syncthreads();
    int woff = 0;
    for (int w = 0; w < wv; ++w) woff += wsum[w];
    const int e0 = s - own + woff;
    const int e1 = e0 + v0, e2 = e1 + v1, e3 = e2 + v2;
    if (base + 3 < NNODES) {
        *(int4*)(excl + base) = make_int4(e0, e1, e2, e3);
    } else {
        if (base     < NNODES) excl[base]     = e0;
        if (base + 1 < NNODES) excl[base + 1] = e1;
        if (base + 2 < NNODES) excl[base + 2] = e2;
        if (base + 3 < NNODES) excl[base + 3] = e3;
    }
    if (tid == 0) bsum[b] = wsum[0] + wsum[1] + wsum[2] + wsum[3];
}

// ---------------------------------------------------------------------------
// CSR build pass 2b: exclusive scan of block totals (1 block).
// ---------------------------------------------------------------------------
__global__ __launch_bounds__(128) void scan2_kernel(int* __restrict__ bsum)
{
    const int tid = threadIdx.x;
    int v = (tid < NSB) ? bsum[tid] : 0;
    const int own = v;
    const int lane = tid & 63, wv = tid >> 6;
#pragma unroll
    for (int d = 1; d < 64; d <<= 1) {
        const int t = __shfl_up(v, d);
        if (lane >= d) v += t;
    }
    __shared__ int ws2[2];
    if (lane == 63) ws2[wv] = v;
    __syncthreads();
    if (wv == 1) v += ws2[0];
    if (tid < NSB) bsum[tid] = v - own;
}

// ---------------------------------------------------------------------------
// CSR build pass 2c: add block offsets; produce cursor[].
// ---------------------------------------------------------------------------
__global__ __launch_bounds__(256) void scan3_kernel(
    int* __restrict__ offsets, int* __restrict__ cursor, const int* __restrict__ bsum)
{
    const int tid = threadIdx.x, b = blockIdx.x;
    const int base = b * 1024 + tid * 4;
    const int add = bsum[b];
    if (base + 3 < NNODES) {
        int4 t = *(const int4*)(offsets + base);
        t.x += add; t.y += add; t.z += add; t.w += add;
        *(int4*)(offsets + base) = t;
        *(int4*)(cursor + base) = t;
    } else {
        for (int i = 0; i < 4; ++i)
            if (base + i < NNODES) {
                const int t = offsets[base + i] + add;
                offsets[base + i] = t;
                cursor[base + i] = t;
            }
    }
}

// ---------------------------------------------------------------------------
// CSR build pass 3: scatter self-contained edge records into dst-sorted
// order:  uint4{ src, dst, bf16(e0,e1), bf16(e3, 0) }  (one 16B store).
// ---------------------------------------------------------------------------
__global__ __launch_bounds__(256) void scatter_kernel(
    const int* __restrict__ eidx, const float* __restrict__ eattr,
    int* __restrict__ cursor, uint4* __restrict__ csrE)
{
    const int* dst = eidx + NEDGES;
    for (int e = blockIdx.x * 256 + threadIdx.x; e < NEDGES; e += gridDim.x * 256) {
        const int d = dst[e];
        const float4 ea = ((const float4*)eattr)[e];
        const int slot = atomicAdd(&cursor[d], 1);
        uint4 r;
        r.x = (unsigned)eidx[e];
        r.y = (unsigned)d;
        r.z = pack_bf16(ea.x, ea.y);
        r.w = pack_bf16(ea.w, 0.f);
        csrE[slot] = r;
    }
}

// ---------------------------------------------------------------------------
// Segmented edge kernel: one WAVE per 64-edge dst-sorted run. Coalesced
// th-row reads (16-deep batches), readlane broadcast, segmented flush.
// ---------------------------------------------------------------------------
__global__ __launch_bounds__(256) void seg_edge_kernel(
    const uint4* __restrict__ csrE, const unsigned* __restrict__ th,
    const float* __restrict__ We, unsigned* __restrict__ agg)
{
    const int run = blockIdx.x * 4 + (threadIdx.x >> 6);
    if (run >= NRUNS) return;
    const int lane = threadIdx.x & 63;
    const int c0 = lane * 2, c1 = c0 + 1;

    const float wea0 = We[c0], wea1 = We[H + c0], wea2 = We[2 * H + c0];
    const float web0 = We[c1], web1 = We[H + c1], web2 = We[2 * H + c1];

    const uint4 rec = csrE[(size_t)run * 64 + lane];
    const int mydst = (int)rec.y;

    float acc0 = 0.f, acc1 = 0.f;
    bool first = true;
    int cur = __builtin_amdgcn_readlane(mydst, 0);

#pragma unroll
    for (int sub = 0; sub < 4; ++sub) {
        unsigned rowv[16];
#pragma unroll
        for (int t = 0; t < 16; ++t) {
            const int s = __builtin_amdgcn_readlane((int)rec.x, sub * 16 + t);
            rowv[t] = th[(size_t)s * 64 + lane];
        }
#pragma unroll
        for (int t = 0; t < 16; ++t) {
            const int e = sub * 16 + t;
            const unsigned ue01 = (unsigned)__builtin_amdgcn_readlane((int)rec.z, e);
            const unsigned ue3  = (unsigned)__builtin_amdgcn_readlane((int)rec.w, e);
            const float e0f = __uint_as_float(ue01 << 16);
            const float e1f = __uint_as_float(ue01 & 0xffff0000u);
            const float e3f = __uint_as_float(ue3 << 16);
            const float th0 = __uint_as_float(rowv[t] << 16);
            const float th1 = __uint_as_float(rowv[t] & 0xffff0000u);
            const float w0 = fmaf(e0f, wea0, fmaf(e1f, wea1, e3f * wea2));
            const float w1 = fmaf(e0f, web0, fmaf(e1f, web1, e3f * web2));
            acc0 = fmaf(th0, w0, acc0);
            acc1 = fmaf(th1, w1, acc1);

            const int nxt = (e < 63) ? __builtin_amdgcn_readlane(mydst, e + 1) : -1;
            if (nxt != cur) {
                unsigned* p = agg + (size_t)cur * 64 + lane;
                if (first || e == 63) {
                    unsigned old = *p;
                    while (true) {
                        const float g0 = __uint_as_float(old << 16) + acc0;
                        const float g1 = __uint_as_float(old & 0xffff0000u) + acc1;
                        const unsigned nw = pack_bf16(g0, g1);
                        const unsigned prev = atomicCAS(p, old, nw);
                        if (prev == old) break;
                        old = prev;
                    }
                } else {
                    *p = pack_bf16(acc0, acc1);
                }
                acc0 = 0.f; acc1 = 0.f;
                first = false;
                cur = nxt;
            }
        }
    }
}

// ---------------------------------------------------------------------------
// Node kernel: wave per node, 2ch/lane. ctx via LDS reduce + per-block row.
// ---------------------------------------------------------------------------
__global__ __launch_bounds__(256) void node_kernel(
    const float* __restrict__ x, const float* __restrict__ pos,
    const unsigned* __restrict__ agg,
    const float* __restrict__ Wx, const float* __restrict__ Wp,
    const float* __restrict__ Wout,
    float* __restrict__ out_sup, float* __restrict__ ctx_part)
{
    const int lane = threadIdx.x & 63;
    const int wv   = threadIdx.x >> 6;
    const int c0 = lane * 2, c1 = c0 + 1;

    float wxa[DXI], wxb_[DXI];
#pragma unroll
    for (int k = 0; k < DXI; ++k) { wxa[k] = Wx[k * H + c0]; wxb_[k] = Wx[k * H + c1]; }
    const float wp00 = Wp[c0], wp01 = Wp[H + c0];
    const float wp10 = Wp[c1], wp11 = Wp[H + c1];
    const float woa0 = Wout[c0 * 3], woa1 = Wout[c0 * 3 + 1], woa2 = Wout[c0 * 3 + 2];
    const float wob0 = Wout[c1 * 3], wob1 = Wout[c1 * 3 + 1], wob2 = Wout[c1 * 3 + 2];

    float ctx0 = 0.f, ctx1 = 0.f;

    for (int n = blockIdx.x * 4 + wv; n < NNODES; n += gridDim.x * 4) {
        const unsigned ag = agg[(size_t)n * 64 + lane];
        const float* xr = x + (size_t)n * DXI;
        const float px = pos[(size_t)n * 3], py = pos[(size_t)n * 3 + 1];
        float a0 = fmaf(wp00, px, wp01 * py);
        float a1 = fmaf(wp10, px, wp11 * py);
#pragma unroll
        for (int k = 0; k < DXI; ++k) {
            const float xv = xr[k];
            a0 = fmaf(xv, wxa[k], a0);
            a1 = fmaf(xv, wxb_[k], a1);
        }
        const float h0 = fast_tanh(fast_tanh(a0) + __uint_as_float(ag << 16));
        const float h1 = fast_tanh(fast_tanh(a1) + __uint_as_float(ag & 0xffff0000u));
        ctx0 += h0; ctx1 += h1;

        float p0 = fmaf(h0, woa0, h1 * wob0);
        float p1 = fmaf(h0, woa1, h1 * wob1);
        float p2 = fmaf(h0, woa2, h1 * wob2);
#pragma unroll
        for (int m = 32; m; m >>= 1) {
            p0 += __shfl_xor(p0, m);
            p1 += __shfl_xor(p1, m);
            p2 += __shfl_xor(p2, m);
        }
        if (lane == 0) {
            out_sup[(size_t)n * 3 + 0] = p0;
            out_sup[(size_t)n * 3 + 1] = p1;
            out_sup[(size_t)n * 3 + 2] = p2;
        }
    }

    __shared__ float part[4][H];
    part[wv][c0] = ctx0;
    part[wv][c1] = ctx1;
    __syncthreads();
    if (threadIdx.x < H) {
        const int ch = threadIdx.x;
        ctx_part[(size_t)blockIdx.x * H + ch] =
            part[0][ch] + part[1][ch] + part[2][ch] + part[3][ch];
    }
}

// ---------------------------------------------------------------------------
// ctx finalize: sum per-block partial rows, then tab rows.
// ---------------------------------------------------------------------------
__global__ __launch_bounds__(128) void ctx_kernel(
    const float* __restrict__ ctx_part, const float* __restrict__ W1,
    const float* __restrict__ b1, float* __restrict__ tab)
{
    __shared__ float ctx[H];
    const int ch = threadIdx.x;
    float s0 = 0.f, s1 = 0.f, s2 = 0.f, s3 = 0.f;
#pragma unroll 4
    for (int b = 0; b < NODE_BLOCKS; b += 4) {
        s0 += ctx_part[(size_t)(b + 0) * H + ch];
        s1 += ctx_part[(size_t)(b + 1) * H + ch];
        s2 += ctx_part[(size_t)(b + 2) * H + ch];
        s3 += ctx_part[(size_t)(b + 3) * H + ch];
    }
    ctx[ch] = (s0 + s1 + s2 + s3) * (1.0f / (float)NNODES);
    __syncthreads();
    float acc = b1[ch];
    for (int k = 0; k < H; ++k) acc = fmaf(ctx[k], W1[(size_t)(2 + k) * H + ch], acc);
    const float A0 = W1[ch], A1 = W1[H + ch];
    tab[ch * 8 + 0] = A0;
    tab[ch * 8 + 1] = A1;
    tab[ch * 8 + 2] = acc;
    tab[ch * 8 + 3] = A0 * A0;
    tab[ch * 8 + 4] = A1 * A1;
    tab[ch * 8 + 5] = 0.f;
    tab[ch * 8 + 6] = 0.f;
    tab[ch * 8 + 7] = 0.f;
}

// ---------------------------------------------------------------------------
// Sampling partial kernel: block = 256 thr (4 waves); wave owns an 8-j
// chunk; quarter q = blockIdx&3; lane = point. Grid 2560 = 10 blocks/CU.
// k-loop unrolled x4: scalar loads for 4 iterations issue together (one
// lgkm wait per 4 k's instead of per k).
// ---------------------------------------------------------------------------
__global__ __launch_bounds__(256, 5) void samp_part_kernel(
    const float* __restrict__ dom, const float* __restrict__ bnd,
    const float* __restrict__ tab,
    const float* __restrict__ W2, const float* __restrict__ b2,
    const float* __restrict__ W3, float* __restrict__ sums)
{
    const int tid  = threadIdx.x;
    const int lane = tid & 63;
    const int wv   = __builtin_amdgcn_readfirstlane(tid >> 6);      // 0..3
    const int q    = __builtin_amdgcn_readfirstlane(blockIdx.x & 3);// 0..3
    const int grp  = blockIdx.x >> 2;                               // 0..639
    const int j0   = q * 32 + wv * 8;
    const int p    = grp * 64 + lane;

    float spx, spy;
    if (p < NDOM) { spx = dom[(size_t)p * 2];          spy = dom[(size_t)p * 2 + 1]; }
    else          { spx = bnd[(size_t)(p - NDOM) * 2]; spy = bnd[(size_t)(p - NDOM) * 2 + 1]; }

    float a2[8], d2x[8], d2y[8], exx[8], eyy[8];
#pragma unroll
    for (int jj = 0; jj < 8; ++jj) {
        a2[jj] = b2[j0 + jj];          // uniform -> scalar load
        d2x[jj] = 0.f; d2y[jj] = 0.f; exx[jj] = 0.f; eyy[jj] = 0.f;
    }

    for (int k = 0; k < H; k += 4) {
        // grouped scalar loads for 4 k-iterations
        float wbuf[4][8];
        float tb[4][5];
#pragma unroll
        for (int u = 0; u < 4; ++u) {
            const float* wrow = W2 + (size_t)(k + u) * H + j0;  // uniform
            for (int t = 0; t < 8; ++t) wbuf[u][t] = wrow[t];
            const float* trow = tab + (size_t)(k + u) * 8;      // uniform
            for (int t = 0; t < 5; ++t) tb[u][t] = trow[t];
        }
#pragma unroll
        for (int u = 0; u < 4; ++u) {
            const float A0 = tb[u][0], A1 = tb[u][1], cc = tb[u][2];
            const float A0s = tb[u][3], A1s = tb[u][4];

            const float a1 = fmaf(spx, A0, fmaf(spy, A1, cc));
            const float e  = __builtin_amdgcn_exp2f(a1 * 2.88539008f);
            const float h1 = fmaf(-2.f, __builtin_amdgcn_rcpf(e + 1.f), 1.f);
            const float t1 = fmaf(-h1, h1, 1.f);
            const float m2 = -2.f * h1 * t1;
            const float g1x = t1 * A0, g1y = t1 * A1;
            const float sxx = m2 * A0s, syy = m2 * A1s;

#pragma unroll
            for (int jj = 0; jj < 8; ++jj) {
                const float w = wbuf[u][jj];
                a2[jj]  = fmaf(h1,  w, a2[jj]);
                d2x[jj] = fmaf(g1x, w, d2x[jj]);
                d2y[jj] = fmaf(g1y, w, d2y[jj]);
                exx[jj] = fmaf(sxx, w, exx[jj]);
                eyy[jj] = fmaf(syy, w, eyy[jj]);
            }
        }
    }

    float r[13];
#pragma unroll
    for (int i = 0; i < 13; ++i) r[i] = 0.f;
#pragma unroll
    for (int jj = 0; jj < 8; ++jj) {
        const float h2 = fast_tanh(a2[jj]);
        const float t2 = fmaf(-h2, h2, 1.f);
        const float gx = t2 * d2x[jj];
        const float gy = t2 * d2y[jj];
        const float hxx = fmaf(-2.f * h2 * gx, d2x[jj], t2 * exx[jj]);
        const float hyy = fmaf(-2.f * h2 * gy, d2y[jj], t2 * eyy[jj]);
        const int j = j0 + jj;
        const float w30 = W3[j * 3], w31 = W3[j * 3 + 1], w32 = W3[j * 3 + 2]; // uniform
        r[0]  = fmaf(h2, w30, r[0]);   r[1]  = fmaf(h2, w31, r[1]);   r[2] = fmaf(h2, w32, r[2]);
        r[3]  = fmaf(gx, w30, r[3]);   r[4]  = fmaf(gx, w31, r[4]);   r[5] = fmaf(gx, w32, r[5]);
        r[6]  = fmaf(gy, w30, r[6]);   r[7]  = fmaf(gy, w31, r[7]);   r[8] = fmaf(gy, w32, r[8]);
        r[9]  = fmaf(hxx, w30, r[9]);  r[10] = fmaf(hxx, w31, r[10]);
        r[11] = fmaf(hyy, w30, r[11]); r[12] = fmaf(hyy, w31, r[12]);
    }

    // cross-wave reduction within the quarter
    __shared__ float part[4][64][13];
#pragma unroll
    for (int i = 0; i < 13; ++i) part[wv][lane][i] = r[i];
    __syncthreads();

    if (tid < 64) {
#pragma unroll
        for (int i = 0; i < 13; ++i) {
            const float s = part[0][tid][i] + part[1][tid][i]
                          + part[2][tid][i] + part[3][tid][i];
            sums[((size_t)(q * 13 + i)) * NPTS + grp * 64 + tid] = s; // coalesced
        }
    }
}

// ---------------------------------------------------------------------------
// Sampling epilogue: combine 4 quarter-partials, apply nonlinear physics
// and boundary math. One thread per point.
// ---------------------------------------------------------------------------
__global__ __launch_bounds__(256) void samp_epi_kernel(
    const float* __restrict__ sums, const int* __restrict__ bidx,
    const float* __restrict__ x, const float* __restrict__ xmask,
    float* __restrict__ out)
{
    const int p = blockIdx.x * 256 + threadIdx.x;
    if (p >= NPTS) return;
    float s[13];
#pragma unroll
    for (int i = 0; i < 13; ++i) {
        s[i] = sums[((size_t)(0 * 13 + i)) * NPTS + p]
             + sums[((size_t)(1 * 13 + i)) * NPTS + p]
             + sums[((size_t)(2 * 13 + i)) * NPTS + p]
             + sums[((size_t)(3 * 13 + i)) * NPTS + p];
    }
    const float u = s[0], v = s[1], pp = s[2];
    const float ux = s[3], vx = s[4], px = s[5];
    const float uy = s[6], vy = s[7], py = s[8];
    const float uxx = s[9], vxx = s[10], uyy = s[11], vyy = s[12];
    if (p < NDOM) {
        out[CONT_OFF + p] = ux + vy;
        out[MOMX_OFF + p] = fmaf(u, ux, fmaf(v, uy, px)) - (uxx + uyy) * INV_RE;
        out[MOMY_OFF + p] = fmaf(u, vx, fmaf(v, vy, py)) - (vxx + vyy) * INV_RE;
    } else {
        const int i = p - NDOM;
        const int idx = bidx[i];
        const float* xbp = x + (size_t)idx * DXI;
        const float* mm = xmask + (size_t)idx * 6;
        const float tx = xbp[0], ty = xbp[1];
        const float nx = -ty, ny = tx;
        const float r_vt = fabsf(tx * u + ty * v - xbp[2]) * mm[1];
        const float r_vn = fabsf(nx * u + ny * v - xbp[3]) * mm[2];
        const float r_p  = fabsf(pp - xbp[4]) * mm[3];
        const float r_dv = fabsf(nx * ux + ny * vy - xbp[5]) * mm[4];
        const float r_dp = fabsf(nx * px + ny * py - xbp[6]) * mm[5];
        const float c = mm[1] + mm[2] + mm[3] + mm[4] + mm[5];
        out[BND_OFF + i] = (r_vt + r_vn + r_p + r_dv + r_dp) / c;
    }
}

extern "C" void kernel_launch(void* const* d_in, const int* in_sizes, int n_in,
                              void* d_out, int out_size, void* d_ws, size_t ws_size,
                              hipStream_t stream) {
    const float* x     = (const float*)d_in[0];
    const float* xmask = (const float*)d_in[1];
    const int*   eidx  = (const int*)d_in[2];
    const float* eattr = (const float*)d_in[3];
    const float* pos   = (const float*)d_in[4];
    const float* dom   = (const float*)d_in[6];
    const float* bnd   = (const float*)d_in[7];
    const int*   bidx  = (const int*)d_in[8];
    const float* Wx    = (const float*)d_in[9];
    const float* Wp    = (const float*)d_in[10];
    const float* We    = (const float*)d_in[11];
    const float* Wout  = (const float*)d_in[12];
    const float* W1    = (const float*)d_in[13];
    const float* b1    = (const float*)d_in[14];
    const float* W2    = (const float*)d_in[15];
    const float* b2    = (const float*)d_in[16];
    const float* W3    = (const float*)d_in[17];

    float* out = (float*)d_out;

    // workspace layout (16B-aligned sections): total ~68.9 MB
    int*      counts   = (int*)d_ws;                    // NNODES
    int*      offsets  = counts + NNODES;               // NNODES + 8
    int*      cursor   = offsets + NNODES + 8;          // NNODES
    int*      bsum     = cursor + NNODES;               // 128
    uint4*    csrE     = (uint4*)(bsum + 128);          // NEDGES (16 MB)
    unsigned* th       = (unsigned*)(csrE + NEDGES);    // NNODES*64 (25.6 MB)
    unsigned* agg      = th + (size_t)NNODES * 64;      // NNODES*64 (25.6 MB)
    float*    ctx_part = (float*)(agg + (size_t)NNODES * 64); // NODE_BLOCKS*H (512 KB)
    float*    tab      = ctx_part + (size_t)NODE_BLOCKS * H;  // H*8
    float*    sums     = (float*)th;   // alias: th is dead after seg_edge (8.5 MB used)

    (void)hipMemsetAsync(counts, 0, (size_t)NNODES * sizeof(int), stream);

    hist_th_kernel<<<1024, 256, 0, stream>>>(eidx, x, pos, Wx, Wp, counts, th, (uint4*)agg);
    scan1_kernel<<<NSB, 256, 0, stream>>>(counts, offsets, bsum);
    scan2_kernel<<<1, 128, 0, stream>>>(bsum);
    scan3_kernel<<<NSB, 256, 0, stream>>>(offsets, cursor, bsum);
    scatter_kernel<<<512, 256, 0, stream>>>(eidx, eattr, cursor, csrE);
    seg_edge_kernel<<<(NRUNS + 3) / 4, 256, 0, stream>>>(csrE, th, We, agg);
    node_kernel<<<NODE_BLOCKS, 256, 0, stream>>>(x, pos, agg, Wx, Wp, Wout, out, ctx_part);
    ctx_kernel<<<1, H, 0, stream>>>(ctx_part, W1, b1, tab);
    samp_part_kernel<<<(NPTS / 64) * 4, 256, 0, stream>>>(dom, bnd, tab, W2, b2, W3, sums);
    samp_epi_kernel<<<(NPTS + 255) / 256, 256, 0, stream>>>(sums, bidx, x, xmask, out);
}